// Round 7
// baseline (72.638 us; speedup 1.0000x reference)
//
#include <hip/hip_runtime.h>
#include <math.h>

#define CN 256
#define DN 512

typedef __attribute__((ext_vector_type(8))) short bf16x8;
typedef __attribute__((ext_vector_type(4))) short bf16x4;
typedef __attribute__((ext_vector_type(4))) float f32x4;

__device__ __forceinline__ short f2bf(float f) {
  unsigned u = __float_as_uint(f);
  u += 0x7fffu + ((u >> 16) & 1u);
  return (short)(u >> 16);
}

// 8x f32 -> bf16x8 via v_cvt_pk_bf16_f32 (RNE). Any within-pair ordering of
// the pack is applied identically to A and B fragments, so the MFMA dot
// product over k is invariant — safe by construction.
__device__ __forceinline__ bf16x8 cvt8(float4 lo, float4 hi) {
  union { unsigned u[4]; bf16x8 v; } r;
  asm("v_cvt_pk_bf16_f32 %0, %1, %2" : "=v"(r.u[0]) : "v"(lo.x), "v"(lo.y));
  asm("v_cvt_pk_bf16_f32 %0, %1, %2" : "=v"(r.u[1]) : "v"(lo.z), "v"(lo.w));
  asm("v_cvt_pk_bf16_f32 %0, %1, %2" : "=v"(r.u[2]) : "v"(hi.x), "v"(hi.y));
  asm("v_cvt_pk_bf16_f32 %0, %1, %2" : "=v"(r.u[3]) : "v"(hi.z), "v"(hi.w));
  return r.v;
}

__device__ __forceinline__ float d4(float4 v) {
  return v.x * v.x + v.y * v.y + v.z * v.z + v.w * v.w;
}

struct Pk {
  const float *img_feature, *text, *img, *neg;
  const float *p_t, *aw_t, *ab_t, *p_i, *aw_i, *ab_i;
  const float *W_tt, *b_tt, *W_it, *b_it, *W_ntt, *b_ntt;
  float* out; float* ws;
};

// ---- f32 workspace (float offsets) ----
#define WF_S   0          // 5 x 65536 : S_tt, S_ii, R_it, S_nn, R_nt
#define WF_E   327680     // 3 x 65536 : eT, eI, e0I
#define WF_RP  524288     // 5 x 2048  : relu row-sum partials
#define WF_EC  534528     // 2 x 2048  : exp col-sum partials
#define WF_TW  540672     // 3 x 131072 : text@W_tt, text@W_it, text@W_ntt (f32)
#define WF_BF  933888     // bf16 region start

// ---- bf16 panel region (short offsets) ----
// panel for X[R][K]: 64-row strips; strip = K/32 tiles of 2048 shorts;
// within tile (r,k): ((r>>4)<<9)+((k>>3)<<7)+((r&15)<<3)+(k&7)
#define SB_ETP 0          // 2 x 65536  : eT^T, eI^T [256][256]
#define SB_CP  131072     // 3 x 65536  : c_tt, c_it, c_nt [256][256]
#define SB_HP  327680     // 2 x 65536  : h_t, h_i [256][256]
#define SB_PW  458752     // 5 x 131072 : (p_t@W_tt)^T,(text@W_tt)^T,(p_i@W_it)^T,
                          //              (img@W_it)^T,(neg@W_ntt)^T  [512][256]

__device__ __forceinline__ void mfma_tiles(const short* at, const short* bt,
                                           int wr, int wc, int lane, f32x4 (&acc)[2][2]) {
  const bf16x8 fa0 = *(const bf16x8*)(at + ((wr << 1) << 9) + (lane << 3));
  const bf16x8 fa1 = *(const bf16x8*)(at + (((wr << 1) + 1) << 9) + (lane << 3));
  const bf16x8 fb0 = *(const bf16x8*)(bt + ((wc << 1) << 9) + (lane << 3));
  const bf16x8 fb1 = *(const bf16x8*)(bt + (((wc << 1) + 1) << 9) + (lane << 3));
  acc[0][0] = __builtin_amdgcn_mfma_f32_16x16x32_bf16(fa0, fb0, acc[0][0], 0, 0, 0);
  acc[0][1] = __builtin_amdgcn_mfma_f32_16x16x32_bf16(fa0, fb1, acc[0][1], 0, 0, 0);
  acc[1][0] = __builtin_amdgcn_mfma_f32_16x16x32_bf16(fa1, fb0, acc[1][0], 0, 0, 0);
  acc[1][1] = __builtin_amdgcn_mfma_f32_16x16x32_bf16(fa1, fb1, acc[1][1], 0, 0, 0);
}

__device__ __forceinline__ void reg_nt_gemm(const short* Astrip, const short* Bstrip,
                                            int ntiles, int wr, int wc, int lane,
                                            f32x4 (&acc)[2][2]) {
#pragma unroll 4
  for (int ks = 0; ks < ntiles; ++ks)
    mfma_tiles(Astrip + ks * 2048, Bstrip + ks * 2048, wr, wc, lane, acc);
}

// ---- S1: 8 NT GEMMs from raw f32 (in-reg convert + in-reg norms) +
//          7 pre-GEMMs X@W (in-reg W^T gather) ----
__global__ __launch_bounds__(256) void s1_k(Pk p) {
  float* ws = p.ws;
  short* SH = (short*)(ws + WF_BF);
  __shared__ float invA_lds[64], invB_lds[64];
  const int bid = blockIdx.x, tid = threadIdx.x;
  const int lane = tid & 63, w = tid >> 6, wr = w >> 1, wc = w & 1;

  if (bid < 128) {
    const int job = bid >> 4, tile = bid & 15;
    const int bm = (tile >> 2) << 6, bn = (tile & 3) << 6;
    p.out[4 * CN * DN + bid * 256 + tid] = p.img_feature[bid * 256 + tid];

    const float* XL[7] = {p.text, p.img, p.neg, p.aw_t, p.aw_i, p.p_t, p.p_i};
    const int AM[8] = {0, 1, 0, 2, 0, 0, 1, 0};
    const int BM[8] = {0, 1, 1, 2, 2, 3, 4, 4};
    const float* A = XL[AM[job]];
    const float* B = XL[BM[job]];

    const int ra = bm + (wr << 5) + (lane & 15);
    const int rb = bn + (wc << 5) + (lane & 15);
    const int ko = (lane >> 4) << 3;
    f32x4 acc[2][2] = {};
    float ssa0 = 0.f, ssa1 = 0.f, ssb0 = 0.f, ssb1 = 0.f;
#pragma unroll 2
    for (int ks = 0; ks < 16; ++ks) {
      const int k = (ks << 5) + ko;
      const float4 a0l = *(const float4*)(A + (size_t)ra * 512 + k);
      const float4 a0h = *(const float4*)(A + (size_t)ra * 512 + k + 4);
      const float4 a1l = *(const float4*)(A + (size_t)(ra + 16) * 512 + k);
      const float4 a1h = *(const float4*)(A + (size_t)(ra + 16) * 512 + k + 4);
      const float4 b0l = *(const float4*)(B + (size_t)rb * 512 + k);
      const float4 b0h = *(const float4*)(B + (size_t)rb * 512 + k + 4);
      const float4 b1l = *(const float4*)(B + (size_t)(rb + 16) * 512 + k);
      const float4 b1h = *(const float4*)(B + (size_t)(rb + 16) * 512 + k + 4);
      ssa0 += d4(a0l) + d4(a0h);
      ssa1 += d4(a1l) + d4(a1h);
      ssb0 += d4(b0l) + d4(b0h);
      ssb1 += d4(b1l) + d4(b1h);
      const bf16x8 fa0 = cvt8(a0l, a0h), fa1 = cvt8(a1l, a1h);
      const bf16x8 fb0 = cvt8(b0l, b0h), fb1 = cvt8(b1l, b1h);
      acc[0][0] = __builtin_amdgcn_mfma_f32_16x16x32_bf16(fa0, fb0, acc[0][0], 0, 0, 0);
      acc[0][1] = __builtin_amdgcn_mfma_f32_16x16x32_bf16(fa0, fb1, acc[0][1], 0, 0, 0);
      acc[1][0] = __builtin_amdgcn_mfma_f32_16x16x32_bf16(fa1, fb0, acc[1][0], 0, 0, 0);
      acc[1][1] = __builtin_amdgcn_mfma_f32_16x16x32_bf16(fa1, fb1, acc[1][1], 0, 0, 0);
    }

    float sv[2][2][4];
    if (job < 5) {
      // finish row norms: 4 octet-lanes per row -> xor16 + xor32
      ssa0 += __shfl_xor(ssa0, 16, 64); ssa0 += __shfl_xor(ssa0, 32, 64);
      ssa1 += __shfl_xor(ssa1, 16, 64); ssa1 += __shfl_xor(ssa1, 32, 64);
      ssb0 += __shfl_xor(ssb0, 16, 64); ssb0 += __shfl_xor(ssb0, 32, 64);
      ssb1 += __shfl_xor(ssb1, 16, 64); ssb1 += __shfl_xor(ssb1, 32, 64);
      if (wc == 0 && lane < 16) {
        invA_lds[(wr << 5) + lane]      = 1.f / fmaxf(sqrtf(ssa0), 1e-12f);
        invA_lds[(wr << 5) + 16 + lane] = 1.f / fmaxf(sqrtf(ssa1), 1e-12f);
      }
      if (wr == 0 && lane < 16) {
        invB_lds[(wc << 5) + lane]      = 1.f / fmaxf(sqrtf(ssb0), 1e-12f);
        invB_lds[(wc << 5) + 16 + lane] = 1.f / fmaxf(sqrtf(ssb1), 1e-12f);
      }
      __syncthreads();
      float* C = ws + WF_S + job * 65536;
#pragma unroll
      for (int mi = 0; mi < 2; ++mi)
#pragma unroll
        for (int ni = 0; ni < 2; ++ni) {
          const int cl = (wc << 5) + (ni << 4) + (lane & 15);
#pragma unroll
          for (int jx = 0; jx < 4; ++jx) {
            const int rl = (wr << 5) + (mi << 4) + ((lane >> 4) << 2) + jx;
            const float v = acc[mi][ni][jx] * invA_lds[rl] * invB_lds[cl];
            sv[mi][ni][jx] = v;
            C[(size_t)(bm + rl) * CN + bn + cl] = v;
          }
        }
      float* rp = ws + WF_RP + job * 2048 + ((bn >> 5) + wc) * 256;
#pragma unroll
      for (int mi = 0; mi < 2; ++mi)
#pragma unroll
        for (int jx = 0; jx < 4; ++jx) {
          float s = fmaxf(sv[mi][0][jx], 0.f) + fmaxf(sv[mi][1][jx], 0.f);
          s += __shfl_xor(s, 1, 64); s += __shfl_xor(s, 2, 64);
          s += __shfl_xor(s, 4, 64); s += __shfl_xor(s, 8, 64);
          if ((lane & 15) == 0) {
            const int rl = (wr << 5) + (mi << 4) + ((lane >> 4) << 2) + jx;
            rp[bm + rl] = s;
          }
        }
    } else {
      const int z = job - 5;
      const float* bias = (job == 5) ? p.ab_t : p.ab_i;
      float* C = ws + WF_E + z * 65536;
#pragma unroll
      for (int mi = 0; mi < 2; ++mi)
#pragma unroll
        for (int ni = 0; ni < 2; ++ni) {
          const int cl = (wc << 5) + (ni << 4) + (lane & 15);
          const int rb2 = (wr << 5) + (mi << 4) + ((lane >> 4) << 2);
#pragma unroll
          for (int jx = 0; jx < 4; ++jx) {
            const float v = expf(acc[mi][ni][jx] + bias[bn + cl]);
            sv[mi][ni][jx] = v;
            C[(size_t)(bm + rb2 + jx) * CN + bn + cl] = v;
          }
          if (z < 2) {
            bf16x4 pk;
#pragma unroll
            for (int jx = 0; jx < 4; ++jx) pk[jx] = f2bf(sv[mi][ni][jx]);
            short* ET = SH + SB_ETP + z * 65536 + (bn >> 6) * 16384 + (bm >> 5) * 2048;
            const int idx = (rb2 >> 5) * 2048 + ((cl >> 4) << 9) + (((rb2 & 31) >> 3) << 7)
                          + ((cl & 15) << 3) + (rb2 & 7);
            *(bf16x4*)(ET + idx) = pk;
          }
        }
      if (z < 2) {
        float* ec = ws + WF_EC + z * 2048 + ((bm >> 5) + wr) * 256;
#pragma unroll
        for (int ni = 0; ni < 2; ++ni) {
          float s = 0.f;
#pragma unroll
          for (int mi = 0; mi < 2; ++mi)
#pragma unroll
            for (int jx = 0; jx < 4; ++jx) s += sv[mi][ni][jx];
          s += __shfl_xor(s, 16, 64); s += __shfl_xor(s, 32, 64);
          if ((lane >> 4) == 0) ec[bn + (wc << 5) + (ni << 4) + (lane & 15)] = s;
        }
      }
    }
  } else {
    // pre-GEMMs: X@W, 128x64 out tiles; B = W^T via coalesced dword gathers
    const int t2 = bid - 128, job = t2 >> 4, tile = t2 & 15;
    const int bm = (tile >> 3) << 7, bn = (tile & 7) << 6;
    const float* AR[7] = {p.p_t, p.text, p.p_i, p.img, p.text, p.neg, p.text};
    const float* WR[7] = {p.W_tt, p.W_tt, p.W_it, p.W_it, p.W_it, p.W_ntt, p.W_ntt};
    const int TP[7] = {0, 1, 2, 3, -1, 4, -1};
    const int F32[7] = {-1, 0, -1, -1, 1, -1, 2};
    const float* A = AR[job];
    const float* W = WR[job];
    const int ra = bm + (wr << 6) + (lane & 15);
    const int cb = bn + (wc << 5) + (lane & 15);
    const int ko = (lane >> 4) << 3;
    f32x4 acc[4][2] = {};
#pragma unroll 2
    for (int ks = 0; ks < 16; ++ks) {
      const int k = (ks << 5) + ko;
      bf16x8 af[4];
#pragma unroll
      for (int gi = 0; gi < 4; ++gi) {
        const float4 lo = *(const float4*)(A + (size_t)(ra + gi * 16) * 512 + k);
        const float4 hi = *(const float4*)(A + (size_t)(ra + gi * 16) * 512 + k + 4);
        af[gi] = cvt8(lo, hi);
      }
      float w0[8], w1[8];
#pragma unroll
      for (int j = 0; j < 8; ++j) {
        w0[j] = W[(size_t)(k + j) * 512 + cb];
        w1[j] = W[(size_t)(k + j) * 512 + cb + 16];
      }
      const bf16x8 b0 = cvt8(make_float4(w0[0], w0[1], w0[2], w0[3]),
                             make_float4(w0[4], w0[5], w0[6], w0[7]));
      const bf16x8 b1 = cvt8(make_float4(w1[0], w1[1], w1[2], w1[3]),
                             make_float4(w1[4], w1[5], w1[6], w1[7]));
#pragma unroll
      for (int gi = 0; gi < 4; ++gi) {
        acc[gi][0] = __builtin_amdgcn_mfma_f32_16x16x32_bf16(af[gi], b0, acc[gi][0], 0, 0, 0);
        acc[gi][1] = __builtin_amdgcn_mfma_f32_16x16x32_bf16(af[gi], b1, acc[gi][1], 0, 0, 0);
      }
    }
#pragma unroll
    for (int mi = 0; mi < 4; ++mi)
#pragma unroll
      for (int ni = 0; ni < 2; ++ni) {
        const int c = bn + (wc << 5) + (ni << 4) + (lane & 15);
        const int rb2 = bm + (wr << 6) + (mi << 4) + ((lane >> 4) << 2);
        if (TP[job] >= 0) {
          bf16x4 pk;
#pragma unroll
          for (int jx = 0; jx < 4; ++jx) pk[jx] = f2bf(acc[mi][ni][jx]);
          short* PW = SH + SB_PW + TP[job] * 131072 + (c >> 6) * 16384;
          const int idx = (rb2 >> 5) * 2048 + (((c & 63) >> 4) << 9) + (((rb2 & 31) >> 3) << 7)
                        + ((c & 15) << 3) + (rb2 & 7);
          *(bf16x4*)(PW + idx) = pk;
        }
        if (F32[job] >= 0) {
          float* TW = ws + WF_TW + F32[job] * 131072;
#pragma unroll
          for (int jx = 0; jx < 4; ++jx)
            TW[(size_t)(rb2 + jx) * DN + c] = acc[mi][ni][jx];
        }
      }
  }
}

// ---- S2: g-GEMM (c-strip staged once in LDS) + h->HP; cP builders ----
__global__ __launch_bounds__(256) void s2_k(Pk p) {
  float* ws = p.ws;
  short* SH = (short*)(ws + WF_BF);
  __shared__ __align__(16) short As[16384];
  __shared__ float srs_lds[256], d0_lds[64], E_lds[64];
  const int bid = blockIdx.x, tid = threadIdx.x;
  const int lane = tid & 63, w = tid >> 6, wr = w >> 1, wc = w & 1;

  if (bid < 32) {
    const int job = bid >> 4, tile = bid & 15;
    const int bm = (tile >> 2) << 6, bn = (tile & 3) << 6;
    const float* Araw = ws + WF_S + (job ? 2 : 0) * 65536;
    const float* e0   = ws + WF_E + (job ? 2 : 0) * 65536;
    const short* Bbase = SH + SB_ETP + job * 65536 + (bn >> 6) * 16384;
    {
      const float* rp = ws + WF_RP + (job ? 1 : 0) * 2048;
      float s = 1.f;
#pragma unroll
      for (int tc = 0; tc < 8; ++tc) s += rp[tc * 256 + tid];
      srs_lds[tid] = s;
    }
    if (tid < 64) {
      const float* rp = ws + WF_RP + (job ? 2 : 0) * 2048;
      float s = 2.f;
#pragma unroll
      for (int tc = 0; tc < 8; ++tc) s += rp[tc * 256 + bm + tid];
      d0_lds[tid] = rsqrtf(s);
    } else if (tid < 128) {
      const float* ec = ws + WF_EC + job * 2048;
      float s = 0.f;
#pragma unroll
      for (int tr = 0; tr < 8; ++tr) s += ec[tr * 256 + bn + (tid - 64)];
      E_lds[tid - 64] = s;
    }
    __syncthreads();
    {  // stage whole transformed c-strip (64x256) into LDS, one pass
      const int r = tid >> 2, q = tid & 3;
#pragma unroll
      for (int i = 0; i < 8; ++i) {
        const int k0 = (i << 5) + (q << 3);
        const float* pa = Araw + (size_t)(bm + r) * 256 + k0;
        float x[8];
        *(float4*)&x[0] = *(const float4*)pa;
        *(float4*)&x[4] = *(const float4*)(pa + 4);
        bf16x8 pk;
#pragma unroll
        for (int j = 0; j < 8; ++j) {
          const float rv = fmaxf(x[j], 0.f);
          pk[j] = f2bf(rv * rsqrtf(srs_lds[k0 + j] + rv));
        }
        *(bf16x8*)(As + i * 2048 + ((r >> 4) << 9) + (q << 7) + ((r & 15) << 3)) = pk;
      }
    }
    __syncthreads();
    f32x4 acc[2][2] = {};
#pragma unroll
    for (int i = 0; i < 8; ++i)
      mfma_tiles(As + i * 2048, Bbase + i * 2048, wr, wc, lane, acc);

    short* HP = SH + SB_HP + job * 65536 + (bm >> 6) * 16384 + (bn >> 5) * 2048;
#pragma unroll
    for (int mi = 0; mi < 2; ++mi)
#pragma unroll
      for (int ni = 0; ni < 2; ++ni) {
        const int cl = (wc << 5) + (ni << 4) + (lane & 15);
        const int rb = (wr << 5) + (mi << 4) + ((lane >> 4) << 2);
#pragma unroll
        for (int jx = 0; jx < 4; ++jx) {
          const int rl = rb + jx;
          const size_t gi = (size_t)(bm + rl) * CN + bn + cl;
          const float e = e0[gi];
          const float hv = (2.f * d0_lds[rl] * e + acc[mi][ni][jx]) / (e + E_lds[cl]);
          HP[(cl >> 5) * 2048 + ((rl >> 4) << 9) + (((cl & 31) >> 3) << 7)
             + ((rl & 15) << 3) + (cl & 7)] = f2bf(hv);
        }
      }
  } else {  // cP builders: 3 mats x 4 strips
    const int t2 = bid - 32, z = t2 >> 2, pr = t2 & 3;
    const int SRC[3] = {0, 2, 4};
    const int SRS[3] = {0, 1, 3};
    const float* src = ws + WF_S + SRC[z] * 65536;
    {
      const float* rp = ws + WF_RP + SRS[z] * 2048;
      float s = 1.f;
#pragma unroll
      for (int tc = 0; tc < 8; ++tc) s += rp[tc * 256 + tid];
      srs_lds[tid] = s;
    }
    __syncthreads();
    short* Y = SH + SB_CP + z * 65536 + pr * 16384;
    const int rloc = tid >> 2, q = tid & 3, r = pr * 64 + rloc;
#pragma unroll
    for (int i = 0; i < 8; ++i) {
      const int k0 = q * 8 + i * 32;
      float x[8];
      *(float4*)&x[0] = *(const float4*)(src + (size_t)r * 256 + k0);
      *(float4*)&x[4] = *(const float4*)(src + (size_t)r * 256 + k0 + 4);
      bf16x8 pk;
#pragma unroll
      for (int j = 0; j < 8; ++j) {
        const float rv = fmaxf(x[j], 0.f);
        pk[j] = f2bf(rv * rsqrtf(srs_lds[k0 + j] + rv));
      }
      *(bf16x8*)(Y + i * 2048 + ((rloc >> 4) << 9) + (q << 7) + ((rloc & 15) << 3)) = pk;
    }
  }
}

// ---- S3: out = tanh(d0*(h@PW + c@XW + 2*d0*TW) + bias); job3 = main ----
__global__ __launch_bounds__(256) void s3_k(Pk p) {
  float* ws = p.ws;
  short* SH = (short*)(ws + WF_BF);
  __shared__ float d0a[64], d0b[64];
  const int bid = blockIdx.x, tid = threadIdx.x;
  const int job = bid >> 5, t = bid & 31;
  const int bm = (t >> 3) << 6, bn = (t & 7) << 6;
  const int lane = tid & 63, w = tid >> 6, wr = w >> 1, wc = w & 1;
  const int D0A[4] = {0, 2, 4, 0};
  if (tid < 64) {
    const float* rp = ws + WF_RP + D0A[job] * 2048;
    float s = 2.f;
#pragma unroll
    for (int tc = 0; tc < 8; ++tc) s += rp[tc * 256 + bm + tid];
    d0a[tid] = rsqrtf(s);
    if (job == 3) {
      const float* rp2 = ws + WF_RP + 2 * 2048;
      float s2 = 2.f;
#pragma unroll
      for (int tc = 0; tc < 8; ++tc) s2 += rp2[tc * 256 + bm + tid];
      d0b[tid] = rsqrtf(s2);
    }
  }
  __syncthreads();

  const int mstrip = bm >> 6, nstrip = bn >> 6;
  if (job < 3) {
    const float* bias = (job == 0) ? p.b_tt : (job == 1) ? p.b_it : p.b_ntt;
    const float* TW = ws + WF_TW + job * 131072;
    float* O = p.out + (size_t)(job + 1) * CN * DN;
    f32x4 acc[2][2] = {};
    if (job == 0) {
      reg_nt_gemm(SH + SB_HP + mstrip * 16384, SH + SB_PW + nstrip * 16384, 8, wr, wc, lane, acc);
      reg_nt_gemm(SH + SB_CP + mstrip * 16384, SH + SB_PW + 131072 + nstrip * 16384, 8, wr, wc, lane, acc);
    } else if (job == 1) {
      reg_nt_gemm(SH + SB_HP + 65536 + mstrip * 16384, SH + SB_PW + 2 * 131072 + nstrip * 16384, 8, wr, wc, lane, acc);
      reg_nt_gemm(SH + SB_CP + 65536 + mstrip * 16384, SH + SB_PW + 3 * 131072 + nstrip * 16384, 8, wr, wc, lane, acc);
    } else {
      reg_nt_gemm(SH + SB_CP + 131072 + mstrip * 16384, SH + SB_PW + 4 * 131072 + nstrip * 16384, 8, wr, wc, lane, acc);
    }
#pragma unroll
    for (int mi = 0; mi < 2; ++mi)
#pragma unroll
      for (int ni = 0; ni < 2; ++ni) {
        const int cl = (wc << 5) + (ni << 4) + (lane & 15);
        const int rb = (wr << 5) + (mi << 4) + ((lane >> 4) << 2);
#pragma unroll
        for (int jx = 0; jx < 4; ++jx) {
          const int rl = rb + jx;
          const size_t idx = (size_t)(bm + rl) * DN + bn + cl;
          const float d = d0a[rl];
          O[idx] = tanhf(d * (acc[mi][ni][jx] + 2.f * d * TW[idx]) + bias[idx]);
        }
      }
  } else {
    f32x4 acc1[2][2] = {}, acc2[2][2] = {};
    reg_nt_gemm(SH + SB_HP + mstrip * 16384, SH + SB_PW + nstrip * 16384, 8, wr, wc, lane, acc1);
    reg_nt_gemm(SH + SB_CP + mstrip * 16384, SH + SB_PW + 131072 + nstrip * 16384, 8, wr, wc, lane, acc1);
    reg_nt_gemm(SH + SB_HP + 65536 + mstrip * 16384, SH + SB_PW + 2 * 131072 + nstrip * 16384, 8, wr, wc, lane, acc2);
    reg_nt_gemm(SH + SB_CP + 65536 + mstrip * 16384, SH + SB_PW + 3 * 131072 + nstrip * 16384, 8, wr, wc, lane, acc2);
    const float* TWtt = ws + WF_TW;
    const float* TWit = ws + WF_TW + 131072;
#pragma unroll
    for (int mi = 0; mi < 2; ++mi)
#pragma unroll
      for (int ni = 0; ni < 2; ++ni) {
        const int cl = (wc << 5) + (ni << 4) + (lane & 15);
        const int rb = (wr << 5) + (mi << 4) + ((lane >> 4) << 2);
#pragma unroll
        for (int jx = 0; jx < 4; ++jx) {
          const int rl = rb + jx;
          const size_t idx = (size_t)(bm + rl) * DN + bn + cl;
          const float da = d0a[rl], db = d0b[rl];
          const float ott = tanhf(da * (acc1[mi][ni][jx] + 2.f * da * TWtt[idx]) + p.b_tt[idx]);
          const float oit = tanhf(db * (acc2[mi][ni][jx] + 2.f * db * TWit[idx]) + p.b_it[idx]);
          p.out[idx] = 0.5f * p.text[idx] + 0.35f * ott + 0.15f * oit;
        }
      }
  }
}

extern "C" void kernel_launch(void* const* d_in, const int* in_sizes, int n_in,
                              void* d_out, int out_size, void* d_ws, size_t ws_size,
                              hipStream_t stream) {
  Pk prm;
  prm.img_feature = (const float*)d_in[0];
  prm.text  = (const float*)d_in[1];
  prm.img   = (const float*)d_in[2];
  prm.neg   = (const float*)d_in[3];
  prm.p_t   = (const float*)d_in[4];
  prm.aw_t  = (const float*)d_in[5];
  prm.ab_t  = (const float*)d_in[6];
  prm.p_i   = (const float*)d_in[7];
  prm.aw_i  = (const float*)d_in[8];
  prm.ab_i  = (const float*)d_in[9];
  prm.W_tt  = (const float*)d_in[10];
  prm.b_tt  = (const float*)d_in[11];
  prm.W_it  = (const float*)d_in[12];
  prm.b_it  = (const float*)d_in[13];
  prm.W_ntt = (const float*)d_in[14];
  prm.b_ntt = (const float*)d_in[15];
  prm.out = (float*)d_out;
  prm.ws  = (float*)d_ws;

  s1_k<<<240, 256, 0, stream>>>(prm);
  s2_k<<<44, 256, 0, stream>>>(prm);
  s3_k<<<128, 256, 0, stream>>>(prm);
}

// Round 8
// 49.367 us; speedup vs baseline: 1.4714x; 1.4714x over previous
//
#include <hip/hip_runtime.h>
#include <math.h>

#define CN 256
#define DN 512

typedef __attribute__((ext_vector_type(8))) short bf16x8;
typedef __attribute__((ext_vector_type(4))) short bf16x4;
typedef __attribute__((ext_vector_type(4))) float f32x4;

__device__ __forceinline__ short f2bf(float f) {
  unsigned u = __float_as_uint(f);
  u += 0x7fffu + ((u >> 16) & 1u);
  return (short)(u >> 16);
}

struct Pk {
  const float *img_feature, *text, *img, *neg;
  const float *p_t, *aw_t, *ab_t, *p_i, *aw_i, *ab_i;
  const float *W_tt, *b_tt, *W_it, *b_it, *W_ntt, *b_ntt;
  float* out; float* ws;
};

// ---- f32 workspace (float offsets) ----
#define WF_S   0          // 5 x 65536 : S_tt, S_ii, R_it, S_nn, R_nt
#define WF_E   327680     // 3 x 65536 : eT, eI, e0I
#define WF_RP  524288     // 5 x 2048  : relu row-sum partials
#define WF_EC  534528     // 2 x 2048  : exp col-sum partials
#define WF_INV 538624     // 3 x 256   : inverse row norms
#define WF_TW  540672     // 3 x 131072 : text@W (f32)
#define WF_BF  933888     // bf16 region start

// ---- bf16 panel region (short offsets) ----
// panel for X[R][K]: 64-row strips; strip = K/32 tiles of 2048 shorts;
// within tile (r,k): ((r>>4)<<9)+((k>>3)<<7)+((r&15)<<3)+(k&7)
#define SB_PLAIN 0          // 7 x 131072 : text,img,neg,aw_t,aw_i,p_t,p_i [256][512]
#define SB_WT    917504     // 3 x 262144 : W^T [512][512]
#define SB_ETP   1703936    // 2 x 65536  : eT^T, eI^T
#define SB_CP    1835008    // 3 x 65536  : c panels
#define SB_HP    2031616    // 2 x 65536  : h panels
#define SB_PW    2162688    // 5 x 131072 : (p_t@W_tt)^T,(text@W_tt)^T,(p_i@W_it)^T,
                            //              (img@W_it)^T,(neg@W_ntt)^T [512][256]

__device__ __forceinline__ void mfma_tiles(const short* at, const short* bt,
                                           int wr, int wc, int lane, f32x4 (&acc)[2][2]) {
  const bf16x8 fa0 = *(const bf16x8*)(at + ((wr << 1) << 9) + (lane << 3));
  const bf16x8 fa1 = *(const bf16x8*)(at + (((wr << 1) + 1) << 9) + (lane << 3));
  const bf16x8 fb0 = *(const bf16x8*)(bt + ((wc << 1) << 9) + (lane << 3));
  const bf16x8 fb1 = *(const bf16x8*)(bt + (((wc << 1) + 1) << 9) + (lane << 3));
  acc[0][0] = __builtin_amdgcn_mfma_f32_16x16x32_bf16(fa0, fb0, acc[0][0], 0, 0, 0);
  acc[0][1] = __builtin_amdgcn_mfma_f32_16x16x32_bf16(fa0, fb1, acc[0][1], 0, 0, 0);
  acc[1][0] = __builtin_amdgcn_mfma_f32_16x16x32_bf16(fa1, fb0, acc[1][0], 0, 0, 0);
  acc[1][1] = __builtin_amdgcn_mfma_f32_16x16x32_bf16(fa1, fb1, acc[1][1], 0, 0, 0);
}

__device__ __forceinline__ void reg_nt_gemm(const short* Astrip, const short* Bstrip,
                                            int ntiles, int wr, int wc, int lane,
                                            f32x4 (&acc)[2][2]) {
#pragma unroll 4
  for (int ks = 0; ks < ntiles; ++ks)
    mfma_tiles(Astrip + ks * 2048, Bstrip + ks * 2048, wr, wc, lane, acc);
}

// ---- P0: build all input panels + row inv-norms (unchanged, 256 thr) ----
__global__ __launch_bounds__(256) void p0_k(Pk p) {
  short* SH = (short*)(p.ws + WF_BF);
  const int bid = blockIdx.x, tid = threadIdx.x;
  if (bid < 28) {
    const int mat = bid >> 2, pr = bid & 3;
    const float* XL[7] = {p.text, p.img, p.neg, p.aw_t, p.aw_i, p.p_t, p.p_i};
    const float* X = XL[mat];
    short* Y = SH + SB_PLAIN + mat * 131072 + pr * 32768;
    const int rloc = tid >> 2, q = tid & 3;
    const int r = pr * 64 + rloc;
    float ss = 0.f;
#pragma unroll
    for (int i = 0; i < 16; ++i) {
      const int k0 = q * 8 + i * 32;
      const float4 v0 = *(const float4*)(X + (size_t)r * 512 + k0);
      const float4 v1 = *(const float4*)(X + (size_t)r * 512 + k0 + 4);
      bf16x8 pk;
      pk[0] = f2bf(v0.x); pk[1] = f2bf(v0.y); pk[2] = f2bf(v0.z); pk[3] = f2bf(v0.w);
      pk[4] = f2bf(v1.x); pk[5] = f2bf(v1.y); pk[6] = f2bf(v1.z); pk[7] = f2bf(v1.w);
      ss += v0.x*v0.x + v0.y*v0.y + v0.z*v0.z + v0.w*v0.w
          + v1.x*v1.x + v1.y*v1.y + v1.z*v1.z + v1.w*v1.w;
      *(bf16x8*)(Y + i * 2048 + ((rloc >> 4) << 9) + (q << 7) + ((rloc & 15) << 3)) = pk;
    }
    if (mat < 3) {
      ss += __shfl_xor(ss, 1, 64);
      ss += __shfl_xor(ss, 2, 64);
      if (q == 0) p.ws[WF_INV + mat * 256 + r] = 1.f / fmaxf(sqrtf(ss), 1e-12f);
    }
  } else {
    const int m = (bid - 28) >> 3, pr = (bid - 28) & 7;
    const float* X = (m == 0) ? p.W_tt : (m == 1) ? p.W_it : p.W_ntt;
    short* Y = SH + SB_WT + m * 262144 + pr * 32768;
    const int lane = tid & 63, wv = tid >> 6;
    const int d = pr * 64 + lane;
#pragma unroll 2
    for (int c = 0; c < 16; ++c) {
      const int m0 = wv * 128 + c * 8;
      bf16x8 pk;
#pragma unroll
      for (int j = 0; j < 8; ++j) pk[j] = f2bf(X[(size_t)(m0 + j) * 512 + d]);
      *(bf16x8*)(Y + (m0 >> 5) * 2048 + ((lane >> 4) << 9) + (((m0 >> 3) & 3) << 7)
                 + ((lane & 15) << 3)) = pk;
    }
  }
}

// ---- S1: 512-thr 8-wave K-split; 8 NT GEMMs + 7 pre-GEMMs ----
__global__ __launch_bounds__(512) void s1_k(Pk p) {
  float* ws = p.ws;
  short* SH = (short*)(ws + WF_BF);
  __shared__ float accx[4][64][32];
  const int bid = blockIdx.x, tid = threadIdx.x;
  const int lane = tid & 63, w = tid >> 6;
  const int q = w & 3, kh = w >> 2;
  const int wr = q >> 1, wc = q & 1;

  if (bid < 128) {
    const int job = bid >> 4, tile = bid & 15;
    const int bm = (tile >> 2) << 6, bn = (tile & 3) << 6;
    if (tid < 256) p.out[4 * CN * DN + bid * 256 + tid] = p.img_feature[bid * 256 + tid];

    const int AM[8] = {0, 1, 0, 2, 0, 0, 1, 0};
    const int BM[8] = {0, 1, 1, 2, 2, 3, 4, 4};
    f32x4 acc[2][2] = {};
    reg_nt_gemm(SH + SB_PLAIN + AM[job] * 131072 + (bm >> 6) * 32768 + kh * 8 * 2048,
                SH + SB_PLAIN + BM[job] * 131072 + (bn >> 6) * 32768 + kh * 8 * 2048,
                8, wr, wc, lane, acc);
    if (kh) {
#pragma unroll
      for (int mi = 0; mi < 2; ++mi)
#pragma unroll
        for (int ni = 0; ni < 2; ++ni)
#pragma unroll
          for (int jx = 0; jx < 4; ++jx)
            accx[q][lane][(mi * 2 + ni) * 4 + jx] = acc[mi][ni][jx];
    }
    __syncthreads();
    if (kh) return;
#pragma unroll
    for (int mi = 0; mi < 2; ++mi)
#pragma unroll
      for (int ni = 0; ni < 2; ++ni)
#pragma unroll
        for (int jx = 0; jx < 4; ++jx)
          acc[mi][ni][jx] += accx[q][lane][(mi * 2 + ni) * 4 + jx];

    float sv[2][2][4];
    if (job < 5) {
      const float* invA = ws + WF_INV + AM[job] * 256;
      const float* invB = ws + WF_INV + BM[job] * 256;
      float* C = ws + WF_S + job * 65536;
#pragma unroll
      for (int mi = 0; mi < 2; ++mi)
#pragma unroll
        for (int ni = 0; ni < 2; ++ni) {
          const int cl = (wc << 5) + (ni << 4) + (lane & 15);
#pragma unroll
          for (int jx = 0; jx < 4; ++jx) {
            const int rl = (wr << 5) + (mi << 4) + ((lane >> 4) << 2) + jx;
            const float v = acc[mi][ni][jx] * invA[bm + rl] * invB[bn + cl];
            sv[mi][ni][jx] = v;
            C[(size_t)(bm + rl) * CN + bn + cl] = v;
          }
        }
      float* rp = ws + WF_RP + job * 2048 + ((bn >> 5) + wc) * 256;
#pragma unroll
      for (int mi = 0; mi < 2; ++mi)
#pragma unroll
        for (int jx = 0; jx < 4; ++jx) {
          float s = fmaxf(sv[mi][0][jx], 0.f) + fmaxf(sv[mi][1][jx], 0.f);
          s += __shfl_xor(s, 1, 64); s += __shfl_xor(s, 2, 64);
          s += __shfl_xor(s, 4, 64); s += __shfl_xor(s, 8, 64);
          if ((lane & 15) == 0) {
            const int rl = (wr << 5) + (mi << 4) + ((lane >> 4) << 2) + jx;
            rp[bm + rl] = s;
          }
        }
    } else {
      const int z = job - 5;
      const float* bias = (job == 5) ? p.ab_t : p.ab_i;
      float* C = ws + WF_E + z * 65536;
#pragma unroll
      for (int mi = 0; mi < 2; ++mi)
#pragma unroll
        for (int ni = 0; ni < 2; ++ni) {
          const int cl = (wc << 5) + (ni << 4) + (lane & 15);
          const int rb2 = (wr << 5) + (mi << 4) + ((lane >> 4) << 2);
#pragma unroll
          for (int jx = 0; jx < 4; ++jx) {
            const float v = expf(acc[mi][ni][jx] + bias[bn + cl]);
            sv[mi][ni][jx] = v;
            C[(size_t)(bm + rb2 + jx) * CN + bn + cl] = v;
          }
          if (z < 2) {
            bf16x4 pk;
#pragma unroll
            for (int jx = 0; jx < 4; ++jx) pk[jx] = f2bf(sv[mi][ni][jx]);
            short* ET = SH + SB_ETP + z * 65536 + (bn >> 6) * 16384 + (bm >> 5) * 2048;
            const int idx = (rb2 >> 5) * 2048 + ((cl >> 4) << 9) + (((rb2 & 31) >> 3) << 7)
                          + ((cl & 15) << 3) + (rb2 & 7);
            *(bf16x4*)(ET + idx) = pk;
          }
        }
      if (z < 2) {
        float* ec = ws + WF_EC + z * 2048 + ((bm >> 5) + wr) * 256;
#pragma unroll
        for (int ni = 0; ni < 2; ++ni) {
          float s = 0.f;
#pragma unroll
          for (int mi = 0; mi < 2; ++mi)
#pragma unroll
            for (int jx = 0; jx < 4; ++jx) s += sv[mi][ni][jx];
          s += __shfl_xor(s, 16, 64); s += __shfl_xor(s, 32, 64);
          if ((lane >> 4) == 0) ec[bn + (wc << 5) + (ni << 4) + (lane & 15)] = s;
        }
      }
    }
  } else {
    // pre-GEMMs: X@W, 128x64 out tiles; wave (wr,wc) 64x32, kh K-halves
    const int t2 = bid - 128, job = t2 >> 4, tile = t2 & 15;
    const int bm = (tile >> 3) << 7, bn = (tile & 7) << 6;
    const int AJ[7] = {5, 0, 6, 1, 0, 2, 0};
    const int WJ[7] = {0, 0, 1, 1, 1, 2, 2};
    const int TP[7] = {0, 1, 2, 3, -1, 4, -1};
    const int F32[7] = {-1, 0, -1, -1, 1, -1, 2};
    const short* Astrip = SH + SB_PLAIN + AJ[job] * 131072 + ((bm >> 6) + wr) * 32768;
    const short* Bstrip = SH + SB_WT + WJ[job] * 262144 + (bn >> 6) * 32768;
    f32x4 acc[4][2] = {};
#pragma unroll 2
    for (int ks = kh * 8; ks < kh * 8 + 8; ++ks) {
      const short* at = Astrip + ks * 2048;
      const short* bt = Bstrip + ks * 2048;
      bf16x8 a0 = *(const bf16x8*)(at + (0 << 9) + (lane << 3));
      bf16x8 a1 = *(const bf16x8*)(at + (1 << 9) + (lane << 3));
      bf16x8 a2 = *(const bf16x8*)(at + (2 << 9) + (lane << 3));
      bf16x8 a3 = *(const bf16x8*)(at + (3 << 9) + (lane << 3));
      bf16x8 b0 = *(const bf16x8*)(bt + ((wc << 1) << 9) + (lane << 3));
      bf16x8 b1 = *(const bf16x8*)(bt + (((wc << 1) + 1) << 9) + (lane << 3));
      acc[0][0] = __builtin_amdgcn_mfma_f32_16x16x32_bf16(a0, b0, acc[0][0], 0, 0, 0);
      acc[0][1] = __builtin_amdgcn_mfma_f32_16x16x32_bf16(a0, b1, acc[0][1], 0, 0, 0);
      acc[1][0] = __builtin_amdgcn_mfma_f32_16x16x32_bf16(a1, b0, acc[1][0], 0, 0, 0);
      acc[1][1] = __builtin_amdgcn_mfma_f32_16x16x32_bf16(a1, b1, acc[1][1], 0, 0, 0);
      acc[2][0] = __builtin_amdgcn_mfma_f32_16x16x32_bf16(a2, b0, acc[2][0], 0, 0, 0);
      acc[2][1] = __builtin_amdgcn_mfma_f32_16x16x32_bf16(a2, b1, acc[2][1], 0, 0, 0);
      acc[3][0] = __builtin_amdgcn_mfma_f32_16x16x32_bf16(a3, b0, acc[3][0], 0, 0, 0);
      acc[3][1] = __builtin_amdgcn_mfma_f32_16x16x32_bf16(a3, b1, acc[3][1], 0, 0, 0);
    }
    if (kh) {
#pragma unroll
      for (int mi = 0; mi < 4; ++mi)
#pragma unroll
        for (int ni = 0; ni < 2; ++ni)
#pragma unroll
          for (int jx = 0; jx < 4; ++jx)
            accx[q][lane][(mi * 2 + ni) * 4 + jx] = acc[mi][ni][jx];
    }
    __syncthreads();
    if (kh) return;
#pragma unroll
    for (int mi = 0; mi < 4; ++mi)
#pragma unroll
      for (int ni = 0; ni < 2; ++ni)
#pragma unroll
        for (int jx = 0; jx < 4; ++jx)
          acc[mi][ni][jx] += accx[q][lane][(mi * 2 + ni) * 4 + jx];
#pragma unroll
    for (int mi = 0; mi < 4; ++mi)
#pragma unroll
      for (int ni = 0; ni < 2; ++ni) {
        const int c = bn + (wc << 5) + (ni << 4) + (lane & 15);
        const int rb2 = bm + (wr << 6) + (mi << 4) + ((lane >> 4) << 2);
        if (TP[job] >= 0) {
          bf16x4 pk;
#pragma unroll
          for (int jx = 0; jx < 4; ++jx) pk[jx] = f2bf(acc[mi][ni][jx]);
          short* PW = SH + SB_PW + TP[job] * 131072 + (c >> 6) * 16384;
          const int idx = (rb2 >> 5) * 2048 + (((c & 63) >> 4) << 9) + (((rb2 & 31) >> 3) << 7)
                        + ((c & 15) << 3) + (rb2 & 7);
          *(bf16x4*)(PW + idx) = pk;
        }
        if (F32[job] >= 0) {
          float* TW = ws + WF_TW + F32[job] * 131072;
#pragma unroll
          for (int jx = 0; jx < 4; ++jx)
            TW[(size_t)(rb2 + jx) * DN + c] = acc[mi][ni][jx];
        }
      }
  }
}

// ---- S2: g-GEMM (c-strip staged once, K-split) + h->HP; cP builders ----
__global__ __launch_bounds__(512) void s2_k(Pk p) {
  float* ws = p.ws;
  short* SH = (short*)(ws + WF_BF);
  __shared__ __align__(16) short As[16384];
  __shared__ float accx[4][64][16];
  __shared__ float srs_lds[256], d0_lds[64], E_lds[64];
  const int bid = blockIdx.x, tid = threadIdx.x;
  const int lane = tid & 63, w = tid >> 6;
  const int q = w & 3, kh = w >> 2;
  const int wr = q >> 1, wc = q & 1;

  if (bid < 32) {
    const int job = bid >> 4, tile = bid & 15;
    const int bm = (tile >> 2) << 6, bn = (tile & 3) << 6;
    const float* Araw = ws + WF_S + (job ? 2 : 0) * 65536;
    const float* e0   = ws + WF_E + (job ? 2 : 0) * 65536;
    const short* Bbase = SH + SB_ETP + job * 65536 + (bn >> 6) * 16384;
    if (tid < 256) {
      const float* rp = ws + WF_RP + (job ? 1 : 0) * 2048;
      float s = 1.f;
#pragma unroll
      for (int tc = 0; tc < 8; ++tc) s += rp[tc * 256 + tid];
      srs_lds[tid] = s;
    } else if (tid < 320) {
      const float* rp = ws + WF_RP + (job ? 2 : 0) * 2048;
      float s = 2.f;
#pragma unroll
      for (int tc = 0; tc < 8; ++tc) s += rp[tc * 256 + bm + (tid - 256)];
      d0_lds[tid - 256] = rsqrtf(s);
    } else if (tid < 384) {
      const float* ec = ws + WF_EC + job * 2048;
      float s = 0.f;
#pragma unroll
      for (int tr = 0; tr < 8; ++tr) s += ec[tr * 256 + bn + (tid - 320)];
      E_lds[tid - 320] = s;
    }
    __syncthreads();
    {  // stage transformed c-strip (64x256) into LDS; 512 threads
      const int r = tid >> 3, s8 = tid & 7;
      const int qq = s8 & 3, ih = s8 >> 2;
#pragma unroll
      for (int i = 0; i < 4; ++i) {
        const int ti = i * 2 + ih;
        const int k0 = ti * 32 + (qq << 3);
        const float* pa = Araw + (size_t)(bm + r) * 256 + k0;
        float x[8];
        *(float4*)&x[0] = *(const float4*)pa;
        *(float4*)&x[4] = *(const float4*)(pa + 4);
        bf16x8 pk;
#pragma unroll
        for (int j = 0; j < 8; ++j) {
          const float rv = fmaxf(x[j], 0.f);
          pk[j] = f2bf(rv * rsqrtf(srs_lds[k0 + j] + rv));
        }
        *(bf16x8*)(As + ti * 2048 + ((r >> 4) << 9) + (qq << 7) + ((r & 15) << 3)) = pk;
      }
    }
    __syncthreads();
    f32x4 acc[2][2] = {};
#pragma unroll
    for (int i = kh * 4; i < kh * 4 + 4; ++i)
      mfma_tiles(As + i * 2048, Bbase + i * 2048, wr, wc, lane, acc);
    if (kh) {
#pragma unroll
      for (int mi = 0; mi < 2; ++mi)
#pragma unroll
        for (int ni = 0; ni < 2; ++ni)
#pragma unroll
          for (int jx = 0; jx < 4; ++jx)
            accx[q][lane][(mi * 2 + ni) * 4 + jx] = acc[mi][ni][jx];
    }
    __syncthreads();
    if (kh) return;
#pragma unroll
    for (int mi = 0; mi < 2; ++mi)
#pragma unroll
      for (int ni = 0; ni < 2; ++ni)
#pragma unroll
        for (int jx = 0; jx < 4; ++jx)
          acc[mi][ni][jx] += accx[q][lane][(mi * 2 + ni) * 4 + jx];

    short* HP = SH + SB_HP + job * 65536 + (bm >> 6) * 16384 + (bn >> 5) * 2048;
#pragma unroll
    for (int mi = 0; mi < 2; ++mi)
#pragma unroll
      for (int ni = 0; ni < 2; ++ni) {
        const int cl = (wc << 5) + (ni << 4) + (lane & 15);
        const int rb = (wr << 5) + (mi << 4) + ((lane >> 4) << 2);
#pragma unroll
        for (int jx = 0; jx < 4; ++jx) {
          const int rl = rb + jx;
          const size_t gi = (size_t)(bm + rl) * CN + bn + cl;
          const float e = e0[gi];
          const float hv = (2.f * d0_lds[rl] * e + acc[mi][ni][jx]) / (e + E_lds[cl]);
          HP[(cl >> 5) * 2048 + ((rl >> 4) << 9) + (((cl & 31) >> 3) << 7)
             + ((rl & 15) << 3) + (cl & 7)] = f2bf(hv);
        }
      }
  } else {  // cP builders: 3 mats x 4 strips, 512 threads
    const int t2 = bid - 32, z = t2 >> 2, pr = t2 & 3;
    const int SRC[3] = {0, 2, 4};
    const int SRS[3] = {0, 1, 3};
    const float* src = ws + WF_S + SRC[z] * 65536;
    if (tid < 256) {
      const float* rp = ws + WF_RP + SRS[z] * 2048;
      float s = 1.f;
#pragma unroll
      for (int tc = 0; tc < 8; ++tc) s += rp[tc * 256 + tid];
      srs_lds[tid] = s;
    }
    __syncthreads();
    short* Y = SH + SB_CP + z * 65536 + pr * 16384;
    const int rloc = tid >> 3, s8 = tid & 7;
    const int qq = s8 & 3, ih = s8 >> 2;
    const int r = pr * 64 + rloc;
#pragma unroll
    for (int i = 0; i < 4; ++i) {
      const int ti = i * 2 + ih;
      const int k0 = ti * 32 + (qq << 3);
      float x[8];
      *(float4*)&x[0] = *(const float4*)(src + (size_t)r * 256 + k0);
      *(float4*)&x[4] = *(const float4*)(src + (size_t)r * 256 + k0 + 4);
      bf16x8 pk;
#pragma unroll
      for (int j = 0; j < 8; ++j) {
        const float rv = fmaxf(x[j], 0.f);
        pk[j] = f2bf(rv * rsqrtf(srs_lds[k0 + j] + rv));
      }
      *(bf16x8*)(Y + ti * 2048 + ((rloc >> 4) << 9) + (qq << 7) + ((rloc & 15) << 3)) = pk;
    }
  }
}

// ---- S3: out = tanh(d0*(h@PW + c@XW + 2*d0*TW) + bias); job3 = main ----
__global__ __launch_bounds__(512) void s3_k(Pk p) {
  float* ws = p.ws;
  short* SH = (short*)(ws + WF_BF);
  __shared__ float accx[4][64][16];
  __shared__ float d0a[64], d0b[64];
  const int bid = blockIdx.x, tid = threadIdx.x;
  const int job = bid >> 5, t = bid & 31;
  const int bm = (t >> 3) << 6, bn = (t & 7) << 6;
  const int lane = tid & 63, w = tid >> 6;
  const int q = w & 3, kh = w >> 2;
  const int wr = q >> 1, wc = q & 1;
  const int D0A[4] = {0, 2, 4, 0};
  if (tid < 64) {
    const float* rp = ws + WF_RP + D0A[job] * 2048;
    float s = 2.f;
#pragma unroll
    for (int tc = 0; tc < 8; ++tc) s += rp[tc * 256 + bm + tid];
    d0a[tid] = rsqrtf(s);
  } else if (tid >= 64 && tid < 128 && job == 3) {
    const float* rp2 = ws + WF_RP + 2 * 2048;
    float s2 = 2.f;
#pragma unroll
    for (int tc = 0; tc < 8; ++tc) s2 += rp2[tc * 256 + bm + (tid - 64)];
    d0b[tid - 64] = rsqrtf(s2);
  }
  __syncthreads();

  const int mstrip = bm >> 6, nstrip = bn >> 6;
  f32x4 acc[2][2] = {};
  if (job == 0) {
    if (kh == 0)
      reg_nt_gemm(SH + SB_HP + mstrip * 16384, SH + SB_PW + nstrip * 16384, 8, wr, wc, lane, acc);
    else
      reg_nt_gemm(SH + SB_CP + mstrip * 16384, SH + SB_PW + 131072 + nstrip * 16384, 8, wr, wc, lane, acc);
  } else if (job == 1) {
    if (kh == 0)
      reg_nt_gemm(SH + SB_HP + 65536 + mstrip * 16384, SH + SB_PW + 2 * 131072 + nstrip * 16384, 8, wr, wc, lane, acc);
    else
      reg_nt_gemm(SH + SB_CP + 65536 + mstrip * 16384, SH + SB_PW + 3 * 131072 + nstrip * 16384, 8, wr, wc, lane, acc);
  } else if (job == 2) {
    reg_nt_gemm(SH + SB_CP + 131072 + mstrip * 16384 + kh * 4 * 2048,
                SH + SB_PW + 4 * 131072 + nstrip * 16384 + kh * 4 * 2048, 4, wr, wc, lane, acc);
  } else {
    if (kh == 0) {
      reg_nt_gemm(SH + SB_HP + mstrip * 16384, SH + SB_PW + nstrip * 16384, 8, wr, wc, lane, acc);
      reg_nt_gemm(SH + SB_CP + mstrip * 16384, SH + SB_PW + 131072 + nstrip * 16384, 8, wr, wc, lane, acc);
    } else {
      reg_nt_gemm(SH + SB_HP + 65536 + mstrip * 16384, SH + SB_PW + 2 * 131072 + nstrip * 16384, 8, wr, wc, lane, acc);
      reg_nt_gemm(SH + SB_CP + 65536 + mstrip * 16384, SH + SB_PW + 3 * 131072 + nstrip * 16384, 8, wr, wc, lane, acc);
    }
  }
  if (kh) {
#pragma unroll
    for (int mi = 0; mi < 2; ++mi)
#pragma unroll
      for (int ni = 0; ni < 2; ++ni)
#pragma unroll
        for (int jx = 0; jx < 4; ++jx)
          accx[q][lane][(mi * 2 + ni) * 4 + jx] = acc[mi][ni][jx];
  }
  __syncthreads();
  if (kh) return;

  if (job < 3) {
#pragma unroll
    for (int mi = 0; mi < 2; ++mi)
#pragma unroll
      for (int ni = 0; ni < 2; ++ni)
#pragma unroll
        for (int jx = 0; jx < 4; ++jx)
          acc[mi][ni][jx] += accx[q][lane][(mi * 2 + ni) * 4 + jx];
    const float* bias = (job == 0) ? p.b_tt : (job == 1) ? p.b_it : p.b_ntt;
    const float* TW = ws + WF_TW + job * 131072;
    float* O = p.out + (size_t)(job + 1) * CN * DN;
#pragma unroll
    for (int mi = 0; mi < 2; ++mi)
#pragma unroll
      for (int ni = 0; ni < 2; ++ni) {
        const int cl = (wc << 5) + (ni << 4) + (lane & 15);
        const int rb = (wr << 5) + (mi << 4) + ((lane >> 4) << 2);
#pragma unroll
        for (int jx = 0; jx < 4; ++jx) {
          const int rl = rb + jx;
          const size_t idx = (size_t)(bm + rl) * DN + bn + cl;
          const float d = d0a[rl];
          O[idx] = tanhf(d * (acc[mi][ni][jx] + 2.f * d * TW[idx]) + bias[idx]);
        }
      }
  } else {
    const float* TWtt = ws + WF_TW;
    const float* TWit = ws + WF_TW + 131072;
#pragma unroll
    for (int mi = 0; mi < 2; ++mi)
#pragma unroll
      for (int ni = 0; ni < 2; ++ni) {
        const int cl = (wc << 5) + (ni << 4) + (lane & 15);
        const int rb = (wr << 5) + (mi << 4) + ((lane >> 4) << 2);
#pragma unroll
        for (int jx = 0; jx < 4; ++jx) {
          const int rl = rb + jx;
          const size_t idx = (size_t)(bm + rl) * DN + bn + cl;
          const float da = d0a[rl], db = d0b[rl];
          const float a2 = accx[q][lane][(mi * 2 + ni) * 4 + jx];
          const float ott = tanhf(da * (acc[mi][ni][jx] + 2.f * da * TWtt[idx]) + p.b_tt[idx]);
          const float oit = tanhf(db * (a2 + 2.f * db * TWit[idx]) + p.b_it[idx]);
          p.out[idx] = 0.5f * p.text[idx] + 0.35f * ott + 0.15f * oit;
        }
      }
  }
}

extern "C" void kernel_launch(void* const* d_in, const int* in_sizes, int n_in,
                              void* d_out, int out_size, void* d_ws, size_t ws_size,
                              hipStream_t stream) {
  Pk prm;
  prm.img_feature = (const float*)d_in[0];
  prm.text  = (const float*)d_in[1];
  prm.img   = (const float*)d_in[2];
  prm.neg   = (const float*)d_in[3];
  prm.p_t   = (const float*)d_in[4];
  prm.aw_t  = (const float*)d_in[5];
  prm.ab_t  = (const float*)d_in[6];
  prm.p_i   = (const float*)d_in[7];
  prm.aw_i  = (const float*)d_in[8];
  prm.ab_i  = (const float*)d_in[9];
  prm.W_tt  = (const float*)d_in[10];
  prm.b_tt  = (const float*)d_in[11];
  prm.W_it  = (const float*)d_in[12];
  prm.b_it  = (const float*)d_in[13];
  prm.W_ntt = (const float*)d_in[14];
  prm.b_ntt = (const float*)d_in[15];
  prm.out = (float*)d_out;
  prm.ws  = (float*)d_ws;

  p0_k<<<52, 256, 0, stream>>>(prm);
  s1_k<<<240, 512, 0, stream>>>(prm);
  s2_k<<<44, 512, 0, stream>>>(prm);
  s3_k<<<128, 512, 0, stream>>>(prm);
}

// Round 9
// 47.518 us; speedup vs baseline: 1.5286x; 1.0389x over previous
//
#include <hip/hip_runtime.h>
#include <math.h>

#define CN 256
#define DN 512

typedef __attribute__((ext_vector_type(8))) short bf16x8;
typedef __attribute__((ext_vector_type(4))) short bf16x4;
typedef __attribute__((ext_vector_type(4))) float f32x4;

__device__ __forceinline__ short f2bf(float f) {
  unsigned u = __float_as_uint(f);
  u += 0x7fffu + ((u >> 16) & 1u);
  return (short)(u >> 16);
}

struct Pk {
  const float *img_feature, *text, *img, *neg;
  const float *p_t, *aw_t, *ab_t, *p_i, *aw_i, *ab_i;
  const float *W_tt, *b_tt, *W_it, *b_it, *W_ntt, *b_ntt;
  float* out; float* ws;
};

// ---- f32 workspace (float offsets) ----
#define WF_S   0          // 5 x 65536 : S_tt, S_ii, R_it, S_nn, R_nt
#define WF_E   327680     // 3 x 65536 : eT, eI, e0I
#define WF_RP  524288     // 5 x 2048  : relu row-sum partials
#define WF_EC  534528     // 2 x 2048  : exp col-sum partials
#define WF_INV 538624     // 3 x 256   : inverse row norms
#define WF_TW  540672     // 3 x 131072 : text@W (f32)
#define WF_BF  933888     // bf16 region start
#define WF_GP  2342912    // 3 x 131072 : c@XW partials (f32)

// ---- bf16 panel region (short offsets) ----
// panel for X[R][K]: 64-row strips; strip = K/32 tiles of 2048 shorts;
// within tile (r,k): ((r>>4)<<9)+((k>>3)<<7)+((r&15)<<3)+(k&7)
#define SB_PLAIN 0          // 7 x 131072 : text,img,neg,aw_t,aw_i,p_t,p_i [256][512]
#define SB_WT    917504     // 3 x 262144 : W^T [512][512]
#define SB_ETP   1703936    // 2 x 65536  : eT^T, eI^T
#define SB_HP    1835008    // 2 x 65536  : h panels
#define SB_PW    1966080    // 5 x 131072 : (p_t@W_tt)^T,(text@W_tt)^T,(p_i@W_it)^T,
                            //              (img@W_it)^T,(neg@W_ntt)^T [512][256]

__device__ __forceinline__ void mfma_tiles(const short* at, const short* bt,
                                           int wr, int wc, int lane, f32x4 (&acc)[2][2]) {
  const bf16x8 fa0 = *(const bf16x8*)(at + ((wr << 1) << 9) + (lane << 3));
  const bf16x8 fa1 = *(const bf16x8*)(at + (((wr << 1) + 1) << 9) + (lane << 3));
  const bf16x8 fb0 = *(const bf16x8*)(bt + ((wc << 1) << 9) + (lane << 3));
  const bf16x8 fb1 = *(const bf16x8*)(bt + (((wc << 1) + 1) << 9) + (lane << 3));
  acc[0][0] = __builtin_amdgcn_mfma_f32_16x16x32_bf16(fa0, fb0, acc[0][0], 0, 0, 0);
  acc[0][1] = __builtin_amdgcn_mfma_f32_16x16x32_bf16(fa0, fb1, acc[0][1], 0, 0, 0);
  acc[1][0] = __builtin_amdgcn_mfma_f32_16x16x32_bf16(fa1, fb0, acc[1][0], 0, 0, 0);
  acc[1][1] = __builtin_amdgcn_mfma_f32_16x16x32_bf16(fa1, fb1, acc[1][1], 0, 0, 0);
}

__device__ __forceinline__ void reg_nt_gemm(const short* Astrip, const short* Bstrip,
                                            int ntiles, int wr, int wc, int lane,
                                            f32x4 (&acc)[2][2]) {
#pragma unroll 4
  for (int ks = 0; ks < ntiles; ++ks)
    mfma_tiles(Astrip + ks * 2048, Bstrip + ks * 2048, wr, wc, lane, acc);
}

// ---- P0: build all input panels + row inv-norms ----
__global__ __launch_bounds__(256) void p0_k(Pk p) {
  short* SH = (short*)(p.ws + WF_BF);
  const int bid = blockIdx.x, tid = threadIdx.x;
  if (bid < 28) {
    const int mat = bid >> 2, pr = bid & 3;
    const float* XL[7] = {p.text, p.img, p.neg, p.aw_t, p.aw_i, p.p_t, p.p_i};
    const float* X = XL[mat];
    short* Y = SH + SB_PLAIN + mat * 131072 + pr * 32768;
    const int rloc = tid >> 2, q = tid & 3;
    const int r = pr * 64 + rloc;
    float ss = 0.f;
#pragma unroll
    for (int i = 0; i < 16; ++i) {
      const int k0 = q * 8 + i * 32;
      const float4 v0 = *(const float4*)(X + (size_t)r * 512 + k0);
      const float4 v1 = *(const float4*)(X + (size_t)r * 512 + k0 + 4);
      bf16x8 pk;
      pk[0] = f2bf(v0.x); pk[1] = f2bf(v0.y); pk[2] = f2bf(v0.z); pk[3] = f2bf(v0.w);
      pk[4] = f2bf(v1.x); pk[5] = f2bf(v1.y); pk[6] = f2bf(v1.z); pk[7] = f2bf(v1.w);
      ss += v0.x*v0.x + v0.y*v0.y + v0.z*v0.z + v0.w*v0.w
          + v1.x*v1.x + v1.y*v1.y + v1.z*v1.z + v1.w*v1.w;
      *(bf16x8*)(Y + i * 2048 + ((rloc >> 4) << 9) + (q << 7) + ((rloc & 15) << 3)) = pk;
    }
    if (mat < 3) {
      ss += __shfl_xor(ss, 1, 64);
      ss += __shfl_xor(ss, 2, 64);
      if (q == 0) p.ws[WF_INV + mat * 256 + r] = 1.f / fmaxf(sqrtf(ss), 1e-12f);
    }
  } else {
    const int m = (bid - 28) >> 3, pr = (bid - 28) & 7;
    const float* X = (m == 0) ? p.W_tt : (m == 1) ? p.W_it : p.W_ntt;
    short* Y = SH + SB_WT + m * 262144 + pr * 32768;
    const int lane = tid & 63, wv = tid >> 6;
    const int d = pr * 64 + lane;
#pragma unroll 2
    for (int c = 0; c < 16; ++c) {
      const int m0 = wv * 128 + c * 8;
      bf16x8 pk;
#pragma unroll
      for (int j = 0; j < 8; ++j) pk[j] = f2bf(X[(size_t)(m0 + j) * 512 + d]);
      *(bf16x8*)(Y + (m0 >> 5) * 2048 + ((lane >> 4) << 9) + (((m0 >> 3) & 3) << 7)
                 + ((lane & 15) << 3)) = pk;
    }
  }
}

// ---- S1: 8 NT GEMMs + 7 pre-GEMMs, uniform 64x64 tiles, K-split 8 waves ----
__global__ __launch_bounds__(512) void s1_k(Pk p) {
  float* ws = p.ws;
  short* SH = (short*)(ws + WF_BF);
  __shared__ float accx[4][64][16];
  const int bid = blockIdx.x, tid = threadIdx.x;
  const int lane = tid & 63, w = tid >> 6;
  const int q = w & 3, kh = w >> 2;
  const int wr = q >> 1, wc = q & 1;

  if (bid < 128) {
    const int job = bid >> 4, tile = bid & 15;
    const int bm = (tile >> 2) << 6, bn = (tile & 3) << 6;
    if (tid < 256) p.out[4 * CN * DN + bid * 256 + tid] = p.img_feature[bid * 256 + tid];

    const int AM[8] = {0, 1, 0, 2, 0, 0, 1, 0};
    const int BM[8] = {0, 1, 1, 2, 2, 3, 4, 4};
    f32x4 acc[2][2] = {};
    reg_nt_gemm(SH + SB_PLAIN + AM[job] * 131072 + (bm >> 6) * 32768 + kh * 8 * 2048,
                SH + SB_PLAIN + BM[job] * 131072 + (bn >> 6) * 32768 + kh * 8 * 2048,
                8, wr, wc, lane, acc);
    if (kh) {
#pragma unroll
      for (int mi = 0; mi < 2; ++mi)
#pragma unroll
        for (int ni = 0; ni < 2; ++ni)
#pragma unroll
          for (int jx = 0; jx < 4; ++jx)
            accx[q][lane][(mi * 2 + ni) * 4 + jx] = acc[mi][ni][jx];
    }
    __syncthreads();
    if (kh) return;
#pragma unroll
    for (int mi = 0; mi < 2; ++mi)
#pragma unroll
      for (int ni = 0; ni < 2; ++ni)
#pragma unroll
        for (int jx = 0; jx < 4; ++jx)
          acc[mi][ni][jx] += accx[q][lane][(mi * 2 + ni) * 4 + jx];

    float sv[2][2][4];
    if (job < 5) {
      const float* invA = ws + WF_INV + AM[job] * 256;
      const float* invB = ws + WF_INV + BM[job] * 256;
      float* C = ws + WF_S + job * 65536;
#pragma unroll
      for (int mi = 0; mi < 2; ++mi)
#pragma unroll
        for (int ni = 0; ni < 2; ++ni) {
          const int cl = (wc << 5) + (ni << 4) + (lane & 15);
#pragma unroll
          for (int jx = 0; jx < 4; ++jx) {
            const int rl = (wr << 5) + (mi << 4) + ((lane >> 4) << 2) + jx;
            const float v = acc[mi][ni][jx] * invA[bm + rl] * invB[bn + cl];
            sv[mi][ni][jx] = v;
            C[(size_t)(bm + rl) * CN + bn + cl] = v;
          }
        }
      float* rp = ws + WF_RP + job * 2048 + ((bn >> 5) + wc) * 256;
#pragma unroll
      for (int mi = 0; mi < 2; ++mi)
#pragma unroll
        for (int jx = 0; jx < 4; ++jx) {
          float s = fmaxf(sv[mi][0][jx], 0.f) + fmaxf(sv[mi][1][jx], 0.f);
          s += __shfl_xor(s, 1, 64); s += __shfl_xor(s, 2, 64);
          s += __shfl_xor(s, 4, 64); s += __shfl_xor(s, 8, 64);
          if ((lane & 15) == 0) {
            const int rl = (wr << 5) + (mi << 4) + ((lane >> 4) << 2) + jx;
            rp[bm + rl] = s;
          }
        }
    } else {
      const int z = job - 5;
      const float* bias = (job == 5) ? p.ab_t : p.ab_i;
      float* C = ws + WF_E + z * 65536;
#pragma unroll
      for (int mi = 0; mi < 2; ++mi)
#pragma unroll
        for (int ni = 0; ni < 2; ++ni) {
          const int cl = (wc << 5) + (ni << 4) + (lane & 15);
          const int rb2 = (wr << 5) + (mi << 4) + ((lane >> 4) << 2);
#pragma unroll
          for (int jx = 0; jx < 4; ++jx) {
            const float v = expf(acc[mi][ni][jx] + bias[bn + cl]);
            sv[mi][ni][jx] = v;
            C[(size_t)(bm + rb2 + jx) * CN + bn + cl] = v;
          }
          if (z < 2) {
            bf16x4 pk;
#pragma unroll
            for (int jx = 0; jx < 4; ++jx) pk[jx] = f2bf(sv[mi][ni][jx]);
            short* ET = SH + SB_ETP + z * 65536 + (bn >> 6) * 16384 + (bm >> 5) * 2048;
            const int idx = (rb2 >> 5) * 2048 + ((cl >> 4) << 9) + (((rb2 & 31) >> 3) << 7)
                          + ((cl & 15) << 3) + (rb2 & 7);
            *(bf16x4*)(ET + idx) = pk;
          }
        }
      if (z < 2) {
        float* ec = ws + WF_EC + z * 2048 + ((bm >> 5) + wr) * 256;
#pragma unroll
        for (int ni = 0; ni < 2; ++ni) {
          float s = 0.f;
#pragma unroll
          for (int mi = 0; mi < 2; ++mi)
#pragma unroll
            for (int jx = 0; jx < 4; ++jx) s += sv[mi][ni][jx];
          s += __shfl_xor(s, 16, 64); s += __shfl_xor(s, 32, 64);
          if ((lane >> 4) == 0) ec[bn + (wc << 5) + (ni << 4) + (lane & 15)] = s;
        }
      }
    }
  } else {
    // pre-GEMMs: X@W, 64x64 tiles (4x8 per job), uniform with NT path
    const int t2 = bid - 128, job = t2 >> 5, tile = t2 & 31;
    const int bm = (tile >> 3) << 6, bn = (tile & 7) << 6;
    const int AJ[7] = {5, 0, 6, 1, 0, 2, 0};
    const int WJ[7] = {0, 0, 1, 1, 1, 2, 2};
    const int TP[7] = {0, 1, 2, 3, -1, 4, -1};
    const int F32[7] = {-1, 0, -1, -1, 1, -1, 2};
    f32x4 acc[2][2] = {};
    reg_nt_gemm(SH + SB_PLAIN + AJ[job] * 131072 + (bm >> 6) * 32768 + kh * 8 * 2048,
                SH + SB_WT + WJ[job] * 262144 + (bn >> 6) * 32768 + kh * 8 * 2048,
                8, wr, wc, lane, acc);
    if (kh) {
#pragma unroll
      for (int mi = 0; mi < 2; ++mi)
#pragma unroll
        for (int ni = 0; ni < 2; ++ni)
#pragma unroll
          for (int jx = 0; jx < 4; ++jx)
            accx[q][lane][(mi * 2 + ni) * 4 + jx] = acc[mi][ni][jx];
    }
    __syncthreads();
    if (kh) return;
#pragma unroll
    for (int mi = 0; mi < 2; ++mi)
#pragma unroll
      for (int ni = 0; ni < 2; ++ni)
#pragma unroll
        for (int jx = 0; jx < 4; ++jx)
          acc[mi][ni][jx] += accx[q][lane][(mi * 2 + ni) * 4 + jx];
#pragma unroll
    for (int mi = 0; mi < 2; ++mi)
#pragma unroll
      for (int ni = 0; ni < 2; ++ni) {
        const int c = bn + (wc << 5) + (ni << 4) + (lane & 15);
        const int rb2 = bm + (wr << 5) + (mi << 4) + ((lane >> 4) << 2);
        if (TP[job] >= 0) {
          bf16x4 pk;
#pragma unroll
          for (int jx = 0; jx < 4; ++jx) pk[jx] = f2bf(acc[mi][ni][jx]);
          short* PW = SH + SB_PW + TP[job] * 131072 + (c >> 6) * 16384;
          const int idx = (rb2 >> 5) * 2048 + (((c & 63) >> 4) << 9) + (((rb2 & 31) >> 3) << 7)
                        + ((c & 15) << 3) + (rb2 & 7);
          *(bf16x4*)(PW + idx) = pk;
        }
        if (F32[job] >= 0) {
          float* TW = ws + WF_TW + F32[job] * 131072;
#pragma unroll
          for (int jx = 0; jx < 4; ++jx)
            TW[(size_t)(rb2 + jx) * DN + c] = acc[mi][ni][jx];
        }
      }
  }
}

// ---- S2: g-GEMM -> HP panels; c@XW GEMMs -> GP f32 partials ----
__global__ __launch_bounds__(512) void s2_k(Pk p) {
  float* ws = p.ws;
  short* SH = (short*)(ws + WF_BF);
  __shared__ __align__(16) short As[16384];
  __shared__ float accx[4][64][16];
  __shared__ float srs_lds[256], d0_lds[64], E_lds[64];
  const int bid = blockIdx.x, tid = threadIdx.x;
  const int lane = tid & 63, w = tid >> 6;
  const int q = w & 3, kh = w >> 2;
  const int wr = q >> 1, wc = q & 1;

  if (bid < 32) {
    const int job = bid >> 4, tile = bid & 15;
    const int bm = (tile >> 2) << 6, bn = (tile & 3) << 6;
    const float* Araw = ws + WF_S + (job ? 2 : 0) * 65536;
    const float* e0   = ws + WF_E + (job ? 2 : 0) * 65536;
    const short* Bbase = SH + SB_ETP + job * 65536 + (bn >> 6) * 16384;
    if (tid < 256) {
      const float* rp = ws + WF_RP + (job ? 1 : 0) * 2048;
      float s = 1.f;
#pragma unroll
      for (int tc = 0; tc < 8; ++tc) s += rp[tc * 256 + tid];
      srs_lds[tid] = s;
    } else if (tid < 320) {
      const float* rp = ws + WF_RP + (job ? 2 : 0) * 2048;
      float s = 2.f;
#pragma unroll
      for (int tc = 0; tc < 8; ++tc) s += rp[tc * 256 + bm + (tid - 256)];
      d0_lds[tid - 256] = rsqrtf(s);
    } else if (tid < 384) {
      const float* ec = ws + WF_EC + job * 2048;
      float s = 0.f;
#pragma unroll
      for (int tr = 0; tr < 8; ++tr) s += ec[tr * 256 + bn + (tid - 320)];
      E_lds[tid - 320] = s;
    }
    __syncthreads();
    {
      const int r = tid >> 3, s8 = tid & 7;
      const int qq = s8 & 3, ih = s8 >> 2;
#pragma unroll
      for (int i = 0; i < 4; ++i) {
        const int ti = i * 2 + ih;
        const int k0 = ti * 32 + (qq << 3);
        const float* pa = Araw + (size_t)(bm + r) * 256 + k0;
        float x[8];
        *(float4*)&x[0] = *(const float4*)pa;
        *(float4*)&x[4] = *(const float4*)(pa + 4);
        bf16x8 pk;
#pragma unroll
        for (int j = 0; j < 8; ++j) {
          const float rv = fmaxf(x[j], 0.f);
          pk[j] = f2bf(rv * rsqrtf(srs_lds[k0 + j] + rv));
        }
        *(bf16x8*)(As + ti * 2048 + ((r >> 4) << 9) + (qq << 7) + ((r & 15) << 3)) = pk;
      }
    }
    __syncthreads();
    f32x4 acc[2][2] = {};
#pragma unroll
    for (int i = kh * 4; i < kh * 4 + 4; ++i)
      mfma_tiles(As + i * 2048, Bbase + i * 2048, wr, wc, lane, acc);
    if (kh) {
#pragma unroll
      for (int mi = 0; mi < 2; ++mi)
#pragma unroll
        for (int ni = 0; ni < 2; ++ni)
#pragma unroll
          for (int jx = 0; jx < 4; ++jx)
            accx[q][lane][(mi * 2 + ni) * 4 + jx] = acc[mi][ni][jx];
    }
    __syncthreads();
    if (kh) return;
#pragma unroll
    for (int mi = 0; mi < 2; ++mi)
#pragma unroll
      for (int ni = 0; ni < 2; ++ni)
#pragma unroll
        for (int jx = 0; jx < 4; ++jx)
          acc[mi][ni][jx] += accx[q][lane][(mi * 2 + ni) * 4 + jx];

    short* HP = SH + SB_HP + job * 65536 + (bm >> 6) * 16384 + (bn >> 5) * 2048;
#pragma unroll
    for (int mi = 0; mi < 2; ++mi)
#pragma unroll
      for (int ni = 0; ni < 2; ++ni) {
        const int cl = (wc << 5) + (ni << 4) + (lane & 15);
        const int rb = (wr << 5) + (mi << 4) + ((lane >> 4) << 2);
#pragma unroll
        for (int jx = 0; jx < 4; ++jx) {
          const int rl = rb + jx;
          const size_t gi = (size_t)(bm + rl) * CN + bn + cl;
          const float e = e0[gi];
          const float hv = (2.f * d0_lds[rl] * e + acc[mi][ni][jx]) / (e + E_lds[cl]);
          HP[(cl >> 5) * 2048 + ((rl >> 4) << 9) + (((cl & 31) >> 3) << 7)
             + ((rl & 15) << 3) + (cl & 7)] = f2bf(hv);
        }
      }
  } else {
    // c@XW GEMMs: z in {tt,it,nt}, out [256 batch][512 outcol] f32 -> GP
    const int t2 = bid - 32, z = t2 >> 5, tile = t2 & 31;
    const int bm = (tile >> 3) << 6, bn = (tile & 7) << 6;
    const int SRC[3] = {0, 2, 4};
    const int SRS[3] = {0, 1, 3};
    const int XS[3]  = {1, 3, 4};
    const float* src = ws + WF_S + SRC[z] * 65536;
    if (tid < 256) {
      const float* rp = ws + WF_RP + SRS[z] * 2048;
      float s = 1.f;
#pragma unroll
      for (int tc = 0; tc < 8; ++tc) s += rp[tc * 256 + tid];
      srs_lds[tid] = s;
    }
    __syncthreads();
    {
      const int r = tid >> 3, s8 = tid & 7;
      const int qq = s8 & 3, ih = s8 >> 2;
#pragma unroll
      for (int i = 0; i < 4; ++i) {
        const int ti = i * 2 + ih;
        const int k0 = ti * 32 + (qq << 3);
        const float* pa = src + (size_t)(bm + r) * 256 + k0;
        float x[8];
        *(float4*)&x[0] = *(const float4*)pa;
        *(float4*)&x[4] = *(const float4*)(pa + 4);
        bf16x8 pk;
#pragma unroll
        for (int j = 0; j < 8; ++j) {
          const float rv = fmaxf(x[j], 0.f);
          pk[j] = f2bf(rv * rsqrtf(srs_lds[k0 + j] + rv));
        }
        *(bf16x8*)(As + ti * 2048 + ((r >> 4) << 9) + (qq << 7) + ((r & 15) << 3)) = pk;
      }
    }
    __syncthreads();
    const short* Bbase = SH + SB_PW + XS[z] * 131072 + (bn >> 6) * 16384;
    f32x4 acc[2][2] = {};
#pragma unroll
    for (int i = kh * 4; i < kh * 4 + 4; ++i)
      mfma_tiles(As + i * 2048, Bbase + i * 2048, wr, wc, lane, acc);
    if (kh) {
#pragma unroll
      for (int mi = 0; mi < 2; ++mi)
#pragma unroll
        for (int ni = 0; ni < 2; ++ni)
#pragma unroll
          for (int jx = 0; jx < 4; ++jx)
            accx[q][lane][(mi * 2 + ni) * 4 + jx] = acc[mi][ni][jx];
    }
    __syncthreads();
    if (kh) return;
    float* GP = ws + WF_GP + z * 131072;
#pragma unroll
    for (int mi = 0; mi < 2; ++mi)
#pragma unroll
      for (int ni = 0; ni < 2; ++ni) {
        const int cl = (wc << 5) + (ni << 4) + (lane & 15);
        const int rb = (wr << 5) + (mi << 4) + ((lane >> 4) << 2);
#pragma unroll
        for (int jx = 0; jx < 4; ++jx) {
          const float v = acc[mi][ni][jx] + accx[q][lane][(mi * 2 + ni) * 4 + jx];
          GP[(size_t)(bm + rb + jx) * DN + bn + cl] = v;
        }
      }
  }
}

// ---- S3: out = tanh(d0*(h@PW + GP + 2*d0*TW) + bias); job2 elementwise;
//          job3 = main combine ----
__global__ __launch_bounds__(512) void s3_k(Pk p) {
  float* ws = p.ws;
  short* SH = (short*)(ws + WF_BF);
  __shared__ float accx[4][64][16];
  __shared__ float d0a[64], d0b[64];
  const int bid = blockIdx.x, tid = threadIdx.x;
  const int job = bid >> 5, t = bid & 31;
  const int bm = (t >> 3) << 6, bn = (t & 7) << 6;
  const int lane = tid & 63, w = tid >> 6;
  const int q = w & 3, kh = w >> 2;
  const int wr = q >> 1, wc = q & 1;
  const int D0A[4] = {0, 2, 4, 0};
  if (tid < 64) {
    const float* rp = ws + WF_RP + D0A[job] * 2048;
    float s = 2.f;
#pragma unroll
    for (int tc = 0; tc < 8; ++tc) s += rp[tc * 256 + bm + tid];
    d0a[tid] = rsqrtf(s);
  } else if (tid >= 64 && tid < 128 && job == 3) {
    const float* rp2 = ws + WF_RP + 2 * 2048;
    float s2 = 2.f;
#pragma unroll
    for (int tc = 0; tc < 8; ++tc) s2 += rp2[tc * 256 + bm + (tid - 64)];
    d0b[tid - 64] = rsqrtf(s2);
  }
  __syncthreads();

  if (job == 2) {  // ntt: no h-term -> pure elementwise
    const float* GP = ws + WF_GP + 2 * 131072;
    const float* TW = ws + WF_TW + 2 * 131072;
    float* O = p.out + 3 * (size_t)CN * DN;
#pragma unroll
    for (int e = tid; e < 4096; e += 512) {
      const int r = e >> 6, cc = e & 63;
      const size_t idx = (size_t)(bm + r) * DN + bn + cc;
      const float d = d0a[r];
      O[idx] = tanhf(d * (GP[idx] + 2.f * d * TW[idx]) + p.b_ntt[idx]);
    }
    return;
  }

  const int mstrip = bm >> 6, nstrip = bn >> 6;
  f32x4 acc[2][2] = {};
  if (job == 0) {
    reg_nt_gemm(SH + SB_HP + mstrip * 16384 + kh * 4 * 2048,
                SH + SB_PW + nstrip * 16384 + kh * 4 * 2048, 4, wr, wc, lane, acc);
  } else if (job == 1) {
    reg_nt_gemm(SH + SB_HP + 65536 + mstrip * 16384 + kh * 4 * 2048,
                SH + SB_PW + 2 * 131072 + nstrip * 16384 + kh * 4 * 2048, 4, wr, wc, lane, acc);
  } else {  // job 3: kh0 -> h_t@PW0, kh1 -> h_i@PW2 (full K each)
    if (kh == 0)
      reg_nt_gemm(SH + SB_HP + mstrip * 16384, SH + SB_PW + nstrip * 16384, 8, wr, wc, lane, acc);
    else
      reg_nt_gemm(SH + SB_HP + 65536 + mstrip * 16384,
                  SH + SB_PW + 2 * 131072 + nstrip * 16384, 8, wr, wc, lane, acc);
  }
  if (kh) {
#pragma unroll
    for (int mi = 0; mi < 2; ++mi)
#pragma unroll
      for (int ni = 0; ni < 2; ++ni)
#pragma unroll
        for (int jx = 0; jx < 4; ++jx)
          accx[q][lane][(mi * 2 + ni) * 4 + jx] = acc[mi][ni][jx];
  }
  __syncthreads();
  if (kh) return;

  if (job < 2) {
#pragma unroll
    for (int mi = 0; mi < 2; ++mi)
#pragma unroll
      for (int ni = 0; ni < 2; ++ni)
#pragma unroll
        for (int jx = 0; jx < 4; ++jx)
          acc[mi][ni][jx] += accx[q][lane][(mi * 2 + ni) * 4 + jx];
    const float* bias = (job == 0) ? p.b_tt : p.b_it;
    const float* TW = ws + WF_TW + job * 131072;
    const float* GP = ws + WF_GP + job * 131072;
    float* O = p.out + (size_t)(job + 1) * CN * DN;
#pragma unroll
    for (int mi = 0; mi < 2; ++mi)
#pragma unroll
      for (int ni = 0; ni < 2; ++ni) {
        const int cl = (wc << 5) + (ni << 4) + (lane & 15);
        const int rb = (wr << 5) + (mi << 4) + ((lane >> 4) << 2);
#pragma unroll
        for (int jx = 0; jx < 4; ++jx) {
          const int rl = rb + jx;
          const size_t idx = (size_t)(bm + rl) * DN + bn + cl;
          const float d = d0a[rl];
          O[idx] = tanhf(d * (acc[mi][ni][jx] + GP[idx] + 2.f * d * TW[idx]) + bias[idx]);
        }
      }
  } else {  // job 3: main combine
    const float* TWtt = ws + WF_TW;
    const float* TWit = ws + WF_TW + 131072;
    const float* GPtt = ws + WF_GP;
    const float* GPit = ws + WF_GP + 131072;
#pragma unroll
    for (int mi = 0; mi < 2; ++mi)
#pragma unroll
      for (int ni = 0; ni < 2; ++ni) {
        const int cl = (wc << 5) + (ni << 4) + (lane & 15);
        const int rb = (wr << 5) + (mi << 4) + ((lane >> 4) << 2);
#pragma unroll
        for (int jx = 0; jx < 4; ++jx) {
          const int rl = rb + jx;
          const size_t idx = (size_t)(bm + rl) * DN + bn + cl;
          const float da = d0a[rl], db = d0b[rl];
          const float a2 = accx[q][lane][(mi * 2 + ni) * 4 + jx];
          const float ott = tanhf(da * (acc[mi][ni][jx] + GPtt[idx] + 2.f * da * TWtt[idx]) + p.b_tt[idx]);
          const float oit = tanhf(db * (a2 + GPit[idx] + 2.f * db * TWit[idx]) + p.b_it[idx]);
          p.out[idx] = 0.5f * p.text[idx] + 0.35f * ott + 0.15f * oit;
        }
      }
  }
}

extern "C" void kernel_launch(void* const* d_in, const int* in_sizes, int n_in,
                              void* d_out, int out_size, void* d_ws, size_t ws_size,
                              hipStream_t stream) {
  Pk prm;
  prm.img_feature = (const float*)d_in[0];
  prm.text  = (const float*)d_in[1];
  prm.img   = (const float*)d_in[2];
  prm.neg   = (const float*)d_in[3];
  prm.p_t   = (const float*)d_in[4];
  prm.aw_t  = (const float*)d_in[5];
  prm.ab_t  = (const float*)d_in[6];
  prm.p_i   = (const float*)d_in[7];
  prm.aw_i  = (const float*)d_in[8];
  prm.ab_i  = (const float*)d_in[9];
  prm.W_tt  = (const float*)d_in[10];
  prm.b_tt  = (const float*)d_in[11];
  prm.W_it  = (const float*)d_in[12];
  prm.b_it  = (const float*)d_in[13];
  prm.W_ntt = (const float*)d_in[14];
  prm.b_ntt = (const float*)d_in[15];
  prm.out = (float*)d_out;
  prm.ws  = (float*)d_ws;

  p0_k<<<52, 256, 0, stream>>>(prm);
  s1_k<<<352, 512, 0, stream>>>(prm);
  s2_k<<<128, 512, 0, stream>>>(prm);
  s3_k<<<128, 512, 0, stream>>>(prm);
}

// Round 10
// 41.618 us; speedup vs baseline: 1.7453x; 1.1418x over previous
//
#include <hip/hip_runtime.h>
#include <math.h>

#define CN 256
#define DN 512

typedef __attribute__((ext_vector_type(8))) short bf16x8;
typedef __attribute__((ext_vector_type(4))) short bf16x4;
typedef __attribute__((ext_vector_type(4))) float f32x4;

__device__ __forceinline__ short f2bf(float f) {
  unsigned u = __float_as_uint(f);
  u += 0x7fffu + ((u >> 16) & 1u);
  return (short)(u >> 16);
}

__device__ __forceinline__ bf16x8 pack8(float4 a, float4 b) {
  bf16x8 r;
  r[0] = f2bf(a.x); r[1] = f2bf(a.y); r[2] = f2bf(a.z); r[3] = f2bf(a.w);
  r[4] = f2bf(b.x); r[5] = f2bf(b.y); r[6] = f2bf(b.z); r[7] = f2bf(b.w);
  return r;
}

__device__ __forceinline__ float d4(float4 v) {
  return v.x * v.x + v.y * v.y + v.z * v.z + v.w * v.w;
}

struct Pk {
  const float *img_feature, *text, *img, *neg;
  const float *p_t, *aw_t, *ab_t, *p_i, *aw_i, *ab_i;
  const float *W_tt, *b_tt, *W_it, *b_it, *W_ntt, *b_ntt;
  float* out; float* ws;
};

// ---- f32 workspace (float offsets) ----
#define WF_S   0          // 5 x 65536 : S_tt, S_ii, R_it, S_nn, R_nt
#define WF_E   327680     // 3 x 65536 : eT, eI, e0I
#define WF_RP  524288     // 5 x 2048  : relu row-sum partials
#define WF_EC  534528     // 2 x 2048  : exp col-sum partials
#define WF_TW  540672     // 3 x 131072 : text@W (f32)
#define WF_BF  933888     // bf16 region start
#define WF_GP  2342912    // 3 x 131072 : c@XW partials (f32)

// ---- bf16 panel region (short offsets; SB_PLAIN/SB_WT slots retired) ----
#define SB_ETP   1703936    // 2 x 65536  : eT^T, eI^T
#define SB_HP    1835008    // 2 x 65536  : h panels
#define SB_PW    1966080    // 5 x 131072 : (p_t@W_tt)^T,(text@W_tt)^T,(p_i@W_it)^T,
                            //              (img@W_it)^T,(neg@W_ntt)^T [512][256]

__device__ __forceinline__ void mfma_tiles(const short* at, const short* bt,
                                           int wr, int wc, int lane, f32x4 (&acc)[2][2]) {
  const bf16x8 fa0 = *(const bf16x8*)(at + ((wr << 1) << 9) + (lane << 3));
  const bf16x8 fa1 = *(const bf16x8*)(at + (((wr << 1) + 1) << 9) + (lane << 3));
  const bf16x8 fb0 = *(const bf16x8*)(bt + ((wc << 1) << 9) + (lane << 3));
  const bf16x8 fb1 = *(const bf16x8*)(bt + (((wc << 1) + 1) << 9) + (lane << 3));
  acc[0][0] = __builtin_amdgcn_mfma_f32_16x16x32_bf16(fa0, fb0, acc[0][0], 0, 0, 0);
  acc[0][1] = __builtin_amdgcn_mfma_f32_16x16x32_bf16(fa0, fb1, acc[0][1], 0, 0, 0);
  acc[1][0] = __builtin_amdgcn_mfma_f32_16x16x32_bf16(fa1, fb0, acc[1][0], 0, 0, 0);
  acc[1][1] = __builtin_amdgcn_mfma_f32_16x16x32_bf16(fa1, fb1, acc[1][1], 0, 0, 0);
}

__device__ __forceinline__ void reg_nt_gemm(const short* Astrip, const short* Bstrip,
                                            int ntiles, int wr, int wc, int lane,
                                            f32x4 (&acc)[2][2]) {
#pragma unroll 4
  for (int ks = 0; ks < ntiles; ++ks)
    mfma_tiles(Astrip + ks * 2048, Bstrip + ks * 2048, wr, wc, lane, acc);
}

// ---- S1 (P0 merged): 8 NT GEMMs + 7 pre-GEMMs, in-block LDS staging from
//      raw f32, 64x64 tiles, 512 thr, K-split across kh ----
__global__ __launch_bounds__(512) void s1_k(Pk p) {
  float* ws = p.ws;
  short* SH = (short*)(ws + WF_BF);
  __shared__ __align__(16) short As[8192];   // 64 x 128 bf16 chunk
  __shared__ __align__(16) short Bs[8192];
  __shared__ float accx[4][64][16];
  __shared__ float invA_lds[64], invB_lds[64];
  const int bid = blockIdx.x, tid = threadIdx.x;
  const int lane = tid & 63, w = tid >> 6;
  const int q = w & 3, kh = w >> 2;
  const int wr = q >> 1, wc = q & 1;
  const int sr = (tid & 255) >> 2, sq = tid & 3;   // staging row / k-octet

  const float* XL[7] = {p.text, p.img, p.neg, p.aw_t, p.aw_i, p.p_t, p.p_i};

  if (bid < 128) {
    const int job = bid >> 4, tile = bid & 15;
    const int bm = (tile >> 2) << 6, bn = (tile & 3) << 6;
    if (tid < 256) p.out[4 * CN * DN + bid * 256 + tid] = p.img_feature[bid * 256 + tid];

    const int AM[8] = {0, 1, 0, 2, 0, 0, 1, 0};
    const int BM[8] = {0, 1, 1, 2, 2, 3, 4, 4};
    const float* A = XL[AM[job]];
    const float* B = XL[BM[job]];
    f32x4 acc[2][2] = {};
    float ss = 0.f;
    for (int ck = 0; ck < 4; ++ck) {
      const int ck0 = ck << 7;
      __syncthreads();
      if (tid < 256) {
        const float* src = A + (size_t)(bm + sr) * 512 + ck0 + (sq << 3);
#pragma unroll
        for (int ks = 0; ks < 4; ++ks) {
          const float4 v0 = *(const float4*)(src + ks * 32);
          const float4 v1 = *(const float4*)(src + ks * 32 + 4);
          ss += d4(v0) + d4(v1);
          *(bf16x8*)&As[ks * 2048 + ((sr >> 4) << 9) + (sq << 7) + ((sr & 15) << 3)] = pack8(v0, v1);
        }
      } else {
        const float* src = B + (size_t)(bn + sr) * 512 + ck0 + (sq << 3);
#pragma unroll
        for (int ks = 0; ks < 4; ++ks) {
          const float4 v0 = *(const float4*)(src + ks * 32);
          const float4 v1 = *(const float4*)(src + ks * 32 + 4);
          ss += d4(v0) + d4(v1);
          *(bf16x8*)&Bs[ks * 2048 + ((sr >> 4) << 9) + (sq << 7) + ((sr & 15) << 3)] = pack8(v0, v1);
        }
      }
      __syncthreads();
#pragma unroll
      for (int t3 = kh * 2; t3 < kh * 2 + 2; ++t3)
        mfma_tiles(As + t3 * 2048, Bs + t3 * 2048, wr, wc, lane, acc);
    }

    if (job < 5) {  // finish row norms (full-K coverage per (sr,sq) thread)
      ss += __shfl_xor(ss, 1, 64);
      ss += __shfl_xor(ss, 2, 64);
      if (sq == 0) {
        const float iv = 1.f / fmaxf(sqrtf(ss), 1e-12f);
        if (tid < 256) invA_lds[sr] = iv;
        else           invB_lds[sr] = iv;
      }
    }
    if (kh) {
#pragma unroll
      for (int mi = 0; mi < 2; ++mi)
#pragma unroll
        for (int ni = 0; ni < 2; ++ni)
#pragma unroll
          for (int jx = 0; jx < 4; ++jx)
            accx[q][lane][(mi * 2 + ni) * 4 + jx] = acc[mi][ni][jx];
    }
    __syncthreads();
    if (kh) return;
#pragma unroll
    for (int mi = 0; mi < 2; ++mi)
#pragma unroll
      for (int ni = 0; ni < 2; ++ni)
#pragma unroll
        for (int jx = 0; jx < 4; ++jx)
          acc[mi][ni][jx] += accx[q][lane][(mi * 2 + ni) * 4 + jx];

    float sv[2][2][4];
    if (job < 5) {
      float* C = ws + WF_S + job * 65536;
#pragma unroll
      for (int mi = 0; mi < 2; ++mi)
#pragma unroll
        for (int ni = 0; ni < 2; ++ni) {
          const int cl = (wc << 5) + (ni << 4) + (lane & 15);
#pragma unroll
          for (int jx = 0; jx < 4; ++jx) {
            const int rl = (wr << 5) + (mi << 4) + ((lane >> 4) << 2) + jx;
            const float v = acc[mi][ni][jx] * invA_lds[rl] * invB_lds[cl];
            sv[mi][ni][jx] = v;
            C[(size_t)(bm + rl) * CN + bn + cl] = v;
          }
        }
      float* rp = ws + WF_RP + job * 2048 + ((bn >> 5) + wc) * 256;
#pragma unroll
      for (int mi = 0; mi < 2; ++mi)
#pragma unroll
        for (int jx = 0; jx < 4; ++jx) {
          float s = fmaxf(sv[mi][0][jx], 0.f) + fmaxf(sv[mi][1][jx], 0.f);
          s += __shfl_xor(s, 1, 64); s += __shfl_xor(s, 2, 64);
          s += __shfl_xor(s, 4, 64); s += __shfl_xor(s, 8, 64);
          if ((lane & 15) == 0) {
            const int rl = (wr << 5) + (mi << 4) + ((lane >> 4) << 2) + jx;
            rp[bm + rl] = s;
          }
        }
    } else {
      const int z = job - 5;
      const float* bias = (job == 5) ? p.ab_t : p.ab_i;
      float* C = ws + WF_E + z * 65536;
#pragma unroll
      for (int mi = 0; mi < 2; ++mi)
#pragma unroll
        for (int ni = 0; ni < 2; ++ni) {
          const int cl = (wc << 5) + (ni << 4) + (lane & 15);
          const int rb2 = (wr << 5) + (mi << 4) + ((lane >> 4) << 2);
#pragma unroll
          for (int jx = 0; jx < 4; ++jx) {
            const float v = expf(acc[mi][ni][jx] + bias[bn + cl]);
            sv[mi][ni][jx] = v;
            C[(size_t)(bm + rb2 + jx) * CN + bn + cl] = v;
          }
          if (z < 2) {
            bf16x4 pk;
#pragma unroll
            for (int jx = 0; jx < 4; ++jx) pk[jx] = f2bf(sv[mi][ni][jx]);
            short* ET = SH + SB_ETP + z * 65536 + (bn >> 6) * 16384 + (bm >> 5) * 2048;
            const int idx = (rb2 >> 5) * 2048 + ((cl >> 4) << 9) + (((rb2 & 31) >> 3) << 7)
                          + ((cl & 15) << 3) + (rb2 & 7);
            *(bf16x4*)(ET + idx) = pk;
          }
        }
      if (z < 2) {
        float* ec = ws + WF_EC + z * 2048 + ((bm >> 5) + wr) * 256;
#pragma unroll
        for (int ni = 0; ni < 2; ++ni) {
          float s = 0.f;
#pragma unroll
          for (int mi = 0; mi < 2; ++mi)
#pragma unroll
            for (int jx = 0; jx < 4; ++jx) s += sv[mi][ni][jx];
          s += __shfl_xor(s, 16, 64); s += __shfl_xor(s, 32, 64);
          if ((lane >> 4) == 0) ec[bn + (wc << 5) + (ni << 4) + (lane & 15)] = s;
        }
      }
    }
  } else {
    // pre-GEMMs: X@W, 64x64 tiles; A staged row-major, B = W^T staged via
    // coalesced column reads (lane-consecutive d), one k-tile per upper wave
    const int t2 = bid - 128, job = t2 >> 5, tile = t2 & 31;
    const int bm = (tile >> 3) << 6, bn = (tile & 7) << 6;
    const int AJ[7] = {5, 0, 6, 1, 0, 2, 0};
    const int WJ[7] = {0, 0, 1, 1, 1, 2, 2};
    const int TP[7] = {0, 1, 2, 3, -1, 4, -1};
    const int F32[7] = {-1, 0, -1, -1, 1, -1, 2};
    const float* A = XL[AJ[job]];
    const float* W = (WJ[job] == 0) ? p.W_tt : (WJ[job] == 1) ? p.W_it : p.W_ntt;
    const int wv4 = w & 3;  // upper-wave index for B staging
    f32x4 acc[2][2] = {};
    for (int ck = 0; ck < 4; ++ck) {
      const int ck0 = ck << 7;
      __syncthreads();
      if (tid < 256) {
        const float* src = A + (size_t)(bm + sr) * 512 + ck0 + (sq << 3);
#pragma unroll
        for (int ks = 0; ks < 4; ++ks) {
          const float4 v0 = *(const float4*)(src + ks * 32);
          const float4 v1 = *(const float4*)(src + ks * 32 + 4);
          *(bf16x8*)&As[ks * 2048 + ((sr >> 4) << 9) + (sq << 7) + ((sr & 15) << 3)] = pack8(v0, v1);
        }
      } else {
        const int d = bn + lane;
#pragma unroll
        for (int c = 0; c < 4; ++c) {
          const int m0 = ck0 + wv4 * 32 + c * 8;
          bf16x8 pk;
#pragma unroll
          for (int j = 0; j < 8; ++j) pk[j] = f2bf(W[(size_t)(m0 + j) * 512 + d]);
          *(bf16x8*)&Bs[wv4 * 2048 + ((lane >> 4) << 9) + (c << 7) + ((lane & 15) << 3)] = pk;
        }
      }
      __syncthreads();
#pragma unroll
      for (int t3 = kh * 2; t3 < kh * 2 + 2; ++t3)
        mfma_tiles(As + t3 * 2048, Bs + t3 * 2048, wr, wc, lane, acc);
    }
    if (kh) {
#pragma unroll
      for (int mi = 0; mi < 2; ++mi)
#pragma unroll
        for (int ni = 0; ni < 2; ++ni)
#pragma unroll
          for (int jx = 0; jx < 4; ++jx)
            accx[q][lane][(mi * 2 + ni) * 4 + jx] = acc[mi][ni][jx];
    }
    __syncthreads();
    if (kh) return;
#pragma unroll
    for (int mi = 0; mi < 2; ++mi)
#pragma unroll
      for (int ni = 0; ni < 2; ++ni)
#pragma unroll
        for (int jx = 0; jx < 4; ++jx)
          acc[mi][ni][jx] += accx[q][lane][(mi * 2 + ni) * 4 + jx];
#pragma unroll
    for (int mi = 0; mi < 2; ++mi)
#pragma unroll
      for (int ni = 0; ni < 2; ++ni) {
        const int c = bn + (wc << 5) + (ni << 4) + (lane & 15);
        const int rb2 = bm + (wr << 5) + (mi << 4) + ((lane >> 4) << 2);
        if (TP[job] >= 0) {
          bf16x4 pk;
#pragma unroll
          for (int jx = 0; jx < 4; ++jx) pk[jx] = f2bf(acc[mi][ni][jx]);
          short* PW = SH + SB_PW + TP[job] * 131072 + (c >> 6) * 16384;
          const int idx = (rb2 >> 5) * 2048 + (((c & 63) >> 4) << 9) + (((rb2 & 31) >> 3) << 7)
                        + ((c & 15) << 3) + (rb2 & 7);
          *(bf16x4*)(PW + idx) = pk;
        }
        if (F32[job] >= 0) {
          float* TW = ws + WF_TW + F32[job] * 131072;
#pragma unroll
          for (int jx = 0; jx < 4; ++jx)
            TW[(size_t)(rb2 + jx) * DN + c] = acc[mi][ni][jx];
        }
      }
  }
}

// ---- S2: g-GEMM -> HP panels; c@XW GEMMs -> GP f32 partials ----
__global__ __launch_bounds__(512) void s2_k(Pk p) {
  float* ws = p.ws;
  short* SH = (short*)(ws + WF_BF);
  __shared__ __align__(16) short As[16384];
  __shared__ float accx[4][64][16];
  __shared__ float srs_lds[256], d0_lds[64], E_lds[64];
  const int bid = blockIdx.x, tid = threadIdx.x;
  const int lane = tid & 63, w = tid >> 6;
  const int q = w & 3, kh = w >> 2;
  const int wr = q >> 1, wc = q & 1;

  if (bid < 32) {
    const int job = bid >> 4, tile = bid & 15;
    const int bm = (tile >> 2) << 6, bn = (tile & 3) << 6;
    const float* Araw = ws + WF_S + (job ? 2 : 0) * 65536;
    const float* e0   = ws + WF_E + (job ? 2 : 0) * 65536;
    const short* Bbase = SH + SB_ETP + job * 65536 + (bn >> 6) * 16384;
    if (tid < 256) {
      const float* rp = ws + WF_RP + (job ? 1 : 0) * 2048;
      float s = 1.f;
#pragma unroll
      for (int tc = 0; tc < 8; ++tc) s += rp[tc * 256 + tid];
      srs_lds[tid] = s;
    } else if (tid < 320) {
      const float* rp = ws + WF_RP + (job ? 2 : 0) * 2048;
      float s = 2.f;
#pragma unroll
      for (int tc = 0; tc < 8; ++tc) s += rp[tc * 256 + bm + (tid - 256)];
      d0_lds[tid - 256] = rsqrtf(s);
    } else if (tid < 384) {
      const float* ec = ws + WF_EC + job * 2048;
      float s = 0.f;
#pragma unroll
      for (int tr = 0; tr < 8; ++tr) s += ec[tr * 256 + bn + (tid - 320)];
      E_lds[tid - 320] = s;
    }
    __syncthreads();
    {
      const int r = tid >> 3, s8 = tid & 7;
      const int qq = s8 & 3, ih = s8 >> 2;
#pragma unroll
      for (int i = 0; i < 4; ++i) {
        const int ti = i * 2 + ih;
        const int k0 = ti * 32 + (qq << 3);
        const float* pa = Araw + (size_t)(bm + r) * 256 + k0;
        float x[8];
        *(float4*)&x[0] = *(const float4*)pa;
        *(float4*)&x[4] = *(const float4*)(pa + 4);
        bf16x8 pk;
#pragma unroll
        for (int j = 0; j < 8; ++j) {
          const float rv = fmaxf(x[j], 0.f);
          pk[j] = f2bf(rv * rsqrtf(srs_lds[k0 + j] + rv));
        }
        *(bf16x8*)(As + ti * 2048 + ((r >> 4) << 9) + (qq << 7) + ((r & 15) << 3)) = pk;
      }
    }
    __syncthreads();
    f32x4 acc[2][2] = {};
#pragma unroll
    for (int i = kh * 4; i < kh * 4 + 4; ++i)
      mfma_tiles(As + i * 2048, Bbase + i * 2048, wr, wc, lane, acc);
    if (kh) {
#pragma unroll
      for (int mi = 0; mi < 2; ++mi)
#pragma unroll
        for (int ni = 0; ni < 2; ++ni)
#pragma unroll
          for (int jx = 0; jx < 4; ++jx)
            accx[q][lane][(mi * 2 + ni) * 4 + jx] = acc[mi][ni][jx];
    }
    __syncthreads();
    if (kh) return;
#pragma unroll
    for (int mi = 0; mi < 2; ++mi)
#pragma unroll
      for (int ni = 0; ni < 2; ++ni)
#pragma unroll
        for (int jx = 0; jx < 4; ++jx)
          acc[mi][ni][jx] += accx[q][lane][(mi * 2 + ni) * 4 + jx];

    short* HP = SH + SB_HP + job * 65536 + (bm >> 6) * 16384 + (bn >> 5) * 2048;
#pragma unroll
    for (int mi = 0; mi < 2; ++mi)
#pragma unroll
      for (int ni = 0; ni < 2; ++ni) {
        const int cl = (wc << 5) + (ni << 4) + (lane & 15);
        const int rb = (wr << 5) + (mi << 4) + ((lane >> 4) << 2);
#pragma unroll
        for (int jx = 0; jx < 4; ++jx) {
          const int rl = rb + jx;
          const size_t gi = (size_t)(bm + rl) * CN + bn + cl;
          const float e = e0[gi];
          const float hv = (2.f * d0_lds[rl] * e + acc[mi][ni][jx]) / (e + E_lds[cl]);
          HP[(cl >> 5) * 2048 + ((rl >> 4) << 9) + (((cl & 31) >> 3) << 7)
             + ((rl & 15) << 3) + (cl & 7)] = f2bf(hv);
        }
      }
  } else {
    // c@XW GEMMs: z in {tt,it,nt}, out [256][512] f32 -> GP
    const int t2 = bid - 32, z = t2 >> 5, tile = t2 & 31;
    const int bm = (tile >> 3) << 6, bn = (tile & 7) << 6;
    const int SRC[3] = {0, 2, 4};
    const int SRS[3] = {0, 1, 3};
    const int XS[3]  = {1, 3, 4};
    const float* src = ws + WF_S + SRC[z] * 65536;
    if (tid < 256) {
      const float* rp = ws + WF_RP + SRS[z] * 2048;
      float s = 1.f;
#pragma unroll
      for (int tc = 0; tc < 8; ++tc) s += rp[tc * 256 + tid];
      srs_lds[tid] = s;
    }
    __syncthreads();
    {
      const int r = tid >> 3, s8 = tid & 7;
      const int qq = s8 & 3, ih = s8 >> 2;
#pragma unroll
      for (int i = 0; i < 4; ++i) {
        const int ti = i * 2 + ih;
        const int k0 = ti * 32 + (qq << 3);
        const float* pa = src + (size_t)(bm + r) * 256 + k0;
        float x[8];
        *(float4*)&x[0] = *(const float4*)pa;
        *(float4*)&x[4] = *(const float4*)(pa + 4);
        bf16x8 pk;
#pragma unroll
        for (int j = 0; j < 8; ++j) {
          const float rv = fmaxf(x[j], 0.f);
          pk[j] = f2bf(rv * rsqrtf(srs_lds[k0 + j] + rv));
        }
        *(bf16x8*)(As + ti * 2048 + ((r >> 4) << 9) + (qq << 7) + ((r & 15) << 3)) = pk;
      }
    }
    __syncthreads();
    const short* Bbase = SH + SB_PW + XS[z] * 131072 + (bn >> 6) * 16384;
    f32x4 acc[2][2] = {};
#pragma unroll
    for (int i = kh * 4; i < kh * 4 + 4; ++i)
      mfma_tiles(As + i * 2048, Bbase + i * 2048, wr, wc, lane, acc);
    if (kh) {
#pragma unroll
      for (int mi = 0; mi < 2; ++mi)
#pragma unroll
        for (int ni = 0; ni < 2; ++ni)
#pragma unroll
          for (int jx = 0; jx < 4; ++jx)
            accx[q][lane][(mi * 2 + ni) * 4 + jx] = acc[mi][ni][jx];
    }
    __syncthreads();
    if (kh) return;
    float* GP = ws + WF_GP + z * 131072;
#pragma unroll
    for (int mi = 0; mi < 2; ++mi)
#pragma unroll
      for (int ni = 0; ni < 2; ++ni) {
        const int cl = (wc << 5) + (ni << 4) + (lane & 15);
        const int rb = (wr << 5) + (mi << 4) + ((lane >> 4) << 2);
#pragma unroll
        for (int jx = 0; jx < 4; ++jx) {
          const float v = acc[mi][ni][jx] + accx[q][lane][(mi * 2 + ni) * 4 + jx];
          GP[(size_t)(bm + rb + jx) * DN + bn + cl] = v;
        }
      }
  }
}

// ---- S3: out = tanh(d0*(h@PW + GP + 2*d0*TW) + bias); job2 elementwise;
//          job3 = main combine ----
__global__ __launch_bounds__(512) void s3_k(Pk p) {
  float* ws = p.ws;
  short* SH = (short*)(ws + WF_BF);
  __shared__ float accx[4][64][16];
  __shared__ float d0a[64], d0b[64];
  const int bid = blockIdx.x, tid = threadIdx.x;
  const int job = bid >> 5, t = bid & 31;
  const int bm = (t >> 3) << 6, bn = (t & 7) << 6;
  const int lane = tid & 63, w = tid >> 6;
  const int q = w & 3, kh = w >> 2;
  const int wr = q >> 1, wc = q & 1;
  const int D0A[4] = {0, 2, 4, 0};
  if (tid < 64) {
    const float* rp = ws + WF_RP + D0A[job] * 2048;
    float s = 2.f;
#pragma unroll
    for (int tc = 0; tc < 8; ++tc) s += rp[tc * 256 + bm + tid];
    d0a[tid] = rsqrtf(s);
  } else if (tid >= 64 && tid < 128 && job == 3) {
    const float* rp2 = ws + WF_RP + 2 * 2048;
    float s2 = 2.f;
#pragma unroll
    for (int tc = 0; tc < 8; ++tc) s2 += rp2[tc * 256 + bm + (tid - 64)];
    d0b[tid - 64] = rsqrtf(s2);
  }
  __syncthreads();

  if (job == 2) {  // ntt: no h-term -> pure elementwise
    const float* GP = ws + WF_GP + 2 * 131072;
    const float* TW = ws + WF_TW + 2 * 131072;
    float* O = p.out + 3 * (size_t)CN * DN;
#pragma unroll
    for (int e = tid; e < 4096; e += 512) {
      const int r = e >> 6, cc = e & 63;
      const size_t idx = (size_t)(bm + r) * DN + bn + cc;
      const float d = d0a[r];
      O[idx] = tanhf(d * (GP[idx] + 2.f * d * TW[idx]) + p.b_ntt[idx]);
    }
    return;
  }

  const int mstrip = bm >> 6, nstrip = bn >> 6;
  f32x4 acc[2][2] = {};
  if (job == 0) {
    reg_nt_gemm(SH + SB_HP + mstrip * 16384 + kh * 4 * 2048,
                SH + SB_PW + nstrip * 16384 + kh * 4 * 2048, 4, wr, wc, lane, acc);
  } else if (job == 1) {
    reg_nt_gemm(SH + SB_HP + 65536 + mstrip * 16384 + kh * 4 * 2048,
                SH + SB_PW + 2 * 131072 + nstrip * 16384 + kh * 4 * 2048, 4, wr, wc, lane, acc);
  } else {  // job 3: kh0 -> h_t@PW0, kh1 -> h_i@PW2 (full K each)
    if (kh == 0)
      reg_nt_gemm(SH + SB_HP + mstrip * 16384, SH + SB_PW + nstrip * 16384, 8, wr, wc, lane, acc);
    else
      reg_nt_gemm(SH + SB_HP + 65536 + mstrip * 16384,
                  SH + SB_PW + 2 * 131072 + nstrip * 16384, 8, wr, wc, lane, acc);
  }
  if (kh) {
#pragma unroll
    for (int mi = 0; mi < 2; ++mi)
#pragma unroll
      for (int ni = 0; ni < 2; ++ni)
#pragma unroll
        for (int jx = 0; jx < 4; ++jx)
          accx[q][lane][(mi * 2 + ni) * 4 + jx] = acc[mi][ni][jx];
  }
  __syncthreads();
  if (kh) return;

  if (job < 2) {
#pragma unroll
    for (int mi = 0; mi < 2; ++mi)
#pragma unroll
      for (int ni = 0; ni < 2; ++ni)
#pragma unroll
        for (int jx = 0; jx < 4; ++jx)
          acc[mi][ni][jx] += accx[q][lane][(mi * 2 + ni) * 4 + jx];
    const float* bias = (job == 0) ? p.b_tt : p.b_it;
    const float* TW = ws + WF_TW + job * 131072;
    const float* GP = ws + WF_GP + job * 131072;
    float* O = p.out + (size_t)(job + 1) * CN * DN;
#pragma unroll
    for (int mi = 0; mi < 2; ++mi)
#pragma unroll
      for (int ni = 0; ni < 2; ++ni) {
        const int cl = (wc << 5) + (ni << 4) + (lane & 15);
        const int rb = (wr << 5) + (mi << 4) + ((lane >> 4) << 2);
#pragma unroll
        for (int jx = 0; jx < 4; ++jx) {
          const int rl = rb + jx;
          const size_t idx = (size_t)(bm + rl) * DN + bn + cl;
          const float d = d0a[rl];
          O[idx] = tanhf(d * (acc[mi][ni][jx] + GP[idx] + 2.f * d * TW[idx]) + bias[idx]);
        }
      }
  } else {  // job 3: main combine
    const float* TWtt = ws + WF_TW;
    const float* TWit = ws + WF_TW + 131072;
    const float* GPtt = ws + WF_GP;
    const float* GPit = ws + WF_GP + 131072;
#pragma unroll
    for (int mi = 0; mi < 2; ++mi)
#pragma unroll
      for (int ni = 0; ni < 2; ++ni) {
        const int cl = (wc << 5) + (ni << 4) + (lane & 15);
        const int rb = (wr << 5) + (mi << 4) + ((lane >> 4) << 2);
#pragma unroll
        for (int jx = 0; jx < 4; ++jx) {
          const int rl = rb + jx;
          const size_t idx = (size_t)(bm + rl) * DN + bn + cl;
          const float da = d0a[rl], db = d0b[rl];
          const float a2 = accx[q][lane][(mi * 2 + ni) * 4 + jx];
          const float ott = tanhf(da * (acc[mi][ni][jx] + GPtt[idx] + 2.f * da * TWtt[idx]) + p.b_tt[idx]);
          const float oit = tanhf(db * (a2 + GPit[idx] + 2.f * db * TWit[idx]) + p.b_it[idx]);
          p.out[idx] = 0.5f * p.text[idx] + 0.35f * ott + 0.15f * oit;
        }
      }
  }
}

extern "C" void kernel_launch(void* const* d_in, const int* in_sizes, int n_in,
                              void* d_out, int out_size, void* d_ws, size_t ws_size,
                              hipStream_t stream) {
  Pk prm;
  prm.img_feature = (const float*)d_in[0];
  prm.text  = (const float*)d_in[1];
  prm.img   = (const float*)d_in[2];
  prm.neg   = (const float*)d_in[3];
  prm.p_t   = (const float*)d_in[4];
  prm.aw_t  = (const float*)d_in[5];
  prm.ab_t  = (const float*)d_in[6];
  prm.p_i   = (const float*)d_in[7];
  prm.aw_i  = (const float*)d_in[8];
  prm.ab_i  = (const float*)d_in[9];
  prm.W_tt  = (const float*)d_in[10];
  prm.b_tt  = (const float*)d_in[11];
  prm.W_it  = (const float*)d_in[12];
  prm.b_it  = (const float*)d_in[13];
  prm.W_ntt = (const float*)d_in[14];
  prm.b_ntt = (const float*)d_in[15];
  prm.out = (float*)d_out;
  prm.ws  = (float*)d_ws;

  s1_k<<<352, 512, 0, stream>>>(prm);
  s2_k<<<128, 512, 0, stream>>>(prm);
  s3_k<<<128, 512, 0, stream>>>(prm);
}

// Round 11
// 39.655 us; speedup vs baseline: 1.8318x; 1.0495x over previous
//
#include <hip/hip_runtime.h>
#include <math.h>

#define CN 256
#define DN 512

typedef __attribute__((ext_vector_type(8))) short bf16x8;
typedef __attribute__((ext_vector_type(4))) short bf16x4;
typedef __attribute__((ext_vector_type(4))) float f32x4;

__device__ __forceinline__ short f2bf(float f) {
  unsigned u = __float_as_uint(f);
  u += 0x7fffu + ((u >> 16) & 1u);
  return (short)(u >> 16);
}

__device__ __forceinline__ bf16x8 pack8(float4 a, float4 b) {
  bf16x8 r;
  r[0] = f2bf(a.x); r[1] = f2bf(a.y); r[2] = f2bf(a.z); r[3] = f2bf(a.w);
  r[4] = f2bf(b.x); r[5] = f2bf(b.y); r[6] = f2bf(b.z); r[7] = f2bf(b.w);
  return r;
}

__device__ __forceinline__ float d4(float4 v) {
  return v.x * v.x + v.y * v.y + v.z * v.z + v.w * v.w;
}

struct Pk {
  const float *img_feature, *text, *img, *neg;
  const float *p_t, *aw_t, *ab_t, *p_i, *aw_i, *ab_i;
  const float *W_tt, *b_tt, *W_it, *b_it, *W_ntt, *b_ntt;
  float* out; float* ws;
};

// ---- f32 workspace (float offsets) ----
#define WF_S   0          // 5 x 65536 : S_tt, S_ii, R_it, S_nn, R_nt
#define WF_E   327680     // 3 x 65536 : eT, eI, e0I
#define WF_RP  524288     // 5 x 2048  : relu row-sum partials
#define WF_EC  534528     // 2 x 2048  : exp col-sum partials
#define WF_TW  540672     // 3 x 131072 : text@W (f32)
#define WF_BF  933888     // bf16 region start

// ---- bf16 panel region (short offsets) ----
#define SB_ETP   1703936    // 2 x 65536  : eT^T, eI^T
#define SB_PW    1966080    // 5 x 131072 : (p_t@W_tt)^T,(text@W_tt)^T,(p_i@W_it)^T,
                            //              (img@W_it)^T,(neg@W_ntt)^T [512][256]

__device__ __forceinline__ void mfma_tiles(const short* at, const short* bt,
                                           int wr, int wc, int lane, f32x4 (&acc)[2][2]) {
  const bf16x8 fa0 = *(const bf16x8*)(at + ((wr << 1) << 9) + (lane << 3));
  const bf16x8 fa1 = *(const bf16x8*)(at + (((wr << 1) + 1) << 9) + (lane << 3));
  const bf16x8 fb0 = *(const bf16x8*)(bt + ((wc << 1) << 9) + (lane << 3));
  const bf16x8 fb1 = *(const bf16x8*)(bt + (((wc << 1) + 1) << 9) + (lane << 3));
  acc[0][0] = __builtin_amdgcn_mfma_f32_16x16x32_bf16(fa0, fb0, acc[0][0], 0, 0, 0);
  acc[0][1] = __builtin_amdgcn_mfma_f32_16x16x32_bf16(fa0, fb1, acc[0][1], 0, 0, 0);
  acc[1][0] = __builtin_amdgcn_mfma_f32_16x16x32_bf16(fa1, fb0, acc[1][0], 0, 0, 0);
  acc[1][1] = __builtin_amdgcn_mfma_f32_16x16x32_bf16(fa1, fb1, acc[1][1], 0, 0, 0);
}

// ---- S1: 8 NT GEMMs + 7 pre-GEMMs, in-block LDS staging from raw f32 ----
__global__ __launch_bounds__(512) void s1_k(Pk p) {
  float* ws = p.ws;
  short* SH = (short*)(ws + WF_BF);
  __shared__ __align__(16) short As[8192];
  __shared__ __align__(16) short Bs[8192];
  __shared__ float accx[4][64][16];
  __shared__ float invA_lds[64], invB_lds[64];
  const int bid = blockIdx.x, tid = threadIdx.x;
  const int lane = tid & 63, w = tid >> 6;
  const int q = w & 3, kh = w >> 2;
  const int wr = q >> 1, wc = q & 1;
  const int sr = (tid & 255) >> 2, sq = tid & 3;

  const float* XL[7] = {p.text, p.img, p.neg, p.aw_t, p.aw_i, p.p_t, p.p_i};

  if (bid < 128) {
    const int job = bid >> 4, tile = bid & 15;
    const int bm = (tile >> 2) << 6, bn = (tile & 3) << 6;
    if (tid < 256) p.out[4 * CN * DN + bid * 256 + tid] = p.img_feature[bid * 256 + tid];
    {  // main init: out[0] = 0.5*text (s23 atomically adds 0.35*ott + 0.15*oit)
      const int i0 = bid * 1024 + tid;
      p.out[i0] = 0.5f * p.text[i0];
      p.out[i0 + 512] = 0.5f * p.text[i0 + 512];
    }

    const int AM[8] = {0, 1, 0, 2, 0, 0, 1, 0};
    const int BM[8] = {0, 1, 1, 2, 2, 3, 4, 4};
    const float* A = XL[AM[job]];
    const float* B = XL[BM[job]];
    f32x4 acc[2][2] = {};
    float ss = 0.f;
    for (int ck = 0; ck < 4; ++ck) {
      const int ck0 = ck << 7;
      __syncthreads();
      if (tid < 256) {
        const float* src = A + (size_t)(bm + sr) * 512 + ck0 + (sq << 3);
#pragma unroll
        for (int ks = 0; ks < 4; ++ks) {
          const float4 v0 = *(const float4*)(src + ks * 32);
          const float4 v1 = *(const float4*)(src + ks * 32 + 4);
          ss += d4(v0) + d4(v1);
          *(bf16x8*)&As[ks * 2048 + ((sr >> 4) << 9) + (sq << 7) + ((sr & 15) << 3)] = pack8(v0, v1);
        }
      } else {
        const float* src = B + (size_t)(bn + sr) * 512 + ck0 + (sq << 3);
#pragma unroll
        for (int ks = 0; ks < 4; ++ks) {
          const float4 v0 = *(const float4*)(src + ks * 32);
          const float4 v1 = *(const float4*)(src + ks * 32 + 4);
          ss += d4(v0) + d4(v1);
          *(bf16x8*)&Bs[ks * 2048 + ((sr >> 4) << 9) + (sq << 7) + ((sr & 15) << 3)] = pack8(v0, v1);
        }
      }
      __syncthreads();
#pragma unroll
      for (int t3 = kh * 2; t3 < kh * 2 + 2; ++t3)
        mfma_tiles(As + t3 * 2048, Bs + t3 * 2048, wr, wc, lane, acc);
    }

    if (job < 5) {
      ss += __shfl_xor(ss, 1, 64);
      ss += __shfl_xor(ss, 2, 64);
      if (sq == 0) {
        const float iv = 1.f / fmaxf(sqrtf(ss), 1e-12f);
        if (tid < 256) invA_lds[sr] = iv;
        else           invB_lds[sr] = iv;
      }
    }
    if (kh) {
#pragma unroll
      for (int mi = 0; mi < 2; ++mi)
#pragma unroll
        for (int ni = 0; ni < 2; ++ni)
#pragma unroll
          for (int jx = 0; jx < 4; ++jx)
            accx[q][lane][(mi * 2 + ni) * 4 + jx] = acc[mi][ni][jx];
    }
    __syncthreads();
    if (kh) return;
#pragma unroll
    for (int mi = 0; mi < 2; ++mi)
#pragma unroll
      for (int ni = 0; ni < 2; ++ni)
#pragma unroll
        for (int jx = 0; jx < 4; ++jx)
          acc[mi][ni][jx] += accx[q][lane][(mi * 2 + ni) * 4 + jx];

    float sv[2][2][4];
    if (job < 5) {
      float* C = ws + WF_S + job * 65536;
#pragma unroll
      for (int mi = 0; mi < 2; ++mi)
#pragma unroll
        for (int ni = 0; ni < 2; ++ni) {
          const int cl = (wc << 5) + (ni << 4) + (lane & 15);
#pragma unroll
          for (int jx = 0; jx < 4; ++jx) {
            const int rl = (wr << 5) + (mi << 4) + ((lane >> 4) << 2) + jx;
            const float v = acc[mi][ni][jx] * invA_lds[rl] * invB_lds[cl];
            sv[mi][ni][jx] = v;
            C[(size_t)(bm + rl) * CN + bn + cl] = v;
          }
        }
      float* rp = ws + WF_RP + job * 2048 + ((bn >> 5) + wc) * 256;
#pragma unroll
      for (int mi = 0; mi < 2; ++mi)
#pragma unroll
        for (int jx = 0; jx < 4; ++jx) {
          float s = fmaxf(sv[mi][0][jx], 0.f) + fmaxf(sv[mi][1][jx], 0.f);
          s += __shfl_xor(s, 1, 64); s += __shfl_xor(s, 2, 64);
          s += __shfl_xor(s, 4, 64); s += __shfl_xor(s, 8, 64);
          if ((lane & 15) == 0) {
            const int rl = (wr << 5) + (mi << 4) + ((lane >> 4) << 2) + jx;
            rp[bm + rl] = s;
          }
        }
    } else {
      const int z = job - 5;
      const float* bias = (job == 5) ? p.ab_t : p.ab_i;
      float* C = ws + WF_E + z * 65536;
#pragma unroll
      for (int mi = 0; mi < 2; ++mi)
#pragma unroll
        for (int ni = 0; ni < 2; ++ni) {
          const int cl = (wc << 5) + (ni << 4) + (lane & 15);
          const int rb2 = (wr << 5) + (mi << 4) + ((lane >> 4) << 2);
#pragma unroll
          for (int jx = 0; jx < 4; ++jx) {
            const float v = expf(acc[mi][ni][jx] + bias[bn + cl]);
            sv[mi][ni][jx] = v;
            C[(size_t)(bm + rb2 + jx) * CN + bn + cl] = v;
          }
          if (z < 2) {
            bf16x4 pk;
#pragma unroll
            for (int jx = 0; jx < 4; ++jx) pk[jx] = f2bf(sv[mi][ni][jx]);
            short* ET = SH + SB_ETP + z * 65536 + (bn >> 6) * 16384 + (bm >> 5) * 2048;
            const int idx = (rb2 >> 5) * 2048 + ((cl >> 4) << 9) + (((rb2 & 31) >> 3) << 7)
                          + ((cl & 15) << 3) + (rb2 & 7);
            *(bf16x4*)(ET + idx) = pk;
          }
        }
      if (z < 2) {
        float* ec = ws + WF_EC + z * 2048 + ((bm >> 5) + wr) * 256;
#pragma unroll
        for (int ni = 0; ni < 2; ++ni) {
          float s = 0.f;
#pragma unroll
          for (int mi = 0; mi < 2; ++mi)
#pragma unroll
            for (int jx = 0; jx < 4; ++jx) s += sv[mi][ni][jx];
          s += __shfl_xor(s, 16, 64); s += __shfl_xor(s, 32, 64);
          if ((lane >> 4) == 0) ec[bn + (wc << 5) + (ni << 4) + (lane & 15)] = s;
        }
      }
    }
  } else {
    // pre-GEMMs: X@W, 64x64 tiles
    const int t2 = bid - 128, job = t2 >> 5, tile = t2 & 31;
    const int bm = (tile >> 3) << 6, bn = (tile & 7) << 6;
    const int AJ[7] = {5, 0, 6, 1, 0, 2, 0};
    const int WJ[7] = {0, 0, 1, 1, 1, 2, 2};
    const int TP[7] = {0, 1, 2, 3, -1, 4, -1};
    const int F32[7] = {-1, 0, -1, -1, 1, -1, 2};
    const float* A = XL[AJ[job]];
    const float* W = (WJ[job] == 0) ? p.W_tt : (WJ[job] == 1) ? p.W_it : p.W_ntt;
    const int wv4 = w & 3;
    f32x4 acc[2][2] = {};
    for (int ck = 0; ck < 4; ++ck) {
      const int ck0 = ck << 7;
      __syncthreads();
      if (tid < 256) {
        const float* src = A + (size_t)(bm + sr) * 512 + ck0 + (sq << 3);
#pragma unroll
        for (int ks = 0; ks < 4; ++ks) {
          const float4 v0 = *(const float4*)(src + ks * 32);
          const float4 v1 = *(const float4*)(src + ks * 32 + 4);
          *(bf16x8*)&As[ks * 2048 + ((sr >> 4) << 9) + (sq << 7) + ((sr & 15) << 3)] = pack8(v0, v1);
        }
      } else {
        const int d = bn + lane;
#pragma unroll
        for (int c = 0; c < 4; ++c) {
          const int m0 = ck0 + wv4 * 32 + c * 8;
          bf16x8 pk;
#pragma unroll
          for (int j = 0; j < 8; ++j) pk[j] = f2bf(W[(size_t)(m0 + j) * 512 + d]);
          *(bf16x8*)&Bs[wv4 * 2048 + ((lane >> 4) << 9) + (c << 7) + ((lane & 15) << 3)] = pk;
        }
      }
      __syncthreads();
#pragma unroll
      for (int t3 = kh * 2; t3 < kh * 2 + 2; ++t3)
        mfma_tiles(As + t3 * 2048, Bs + t3 * 2048, wr, wc, lane, acc);
    }
    if (kh) {
#pragma unroll
      for (int mi = 0; mi < 2; ++mi)
#pragma unroll
        for (int ni = 0; ni < 2; ++ni)
#pragma unroll
          for (int jx = 0; jx < 4; ++jx)
            accx[q][lane][(mi * 2 + ni) * 4 + jx] = acc[mi][ni][jx];
    }
    __syncthreads();
    if (kh) return;
#pragma unroll
    for (int mi = 0; mi < 2; ++mi)
#pragma unroll
      for (int ni = 0; ni < 2; ++ni)
#pragma unroll
        for (int jx = 0; jx < 4; ++jx)
          acc[mi][ni][jx] += accx[q][lane][(mi * 2 + ni) * 4 + jx];
#pragma unroll
    for (int mi = 0; mi < 2; ++mi)
#pragma unroll
      for (int ni = 0; ni < 2; ++ni) {
        const int c = bn + (wc << 5) + (ni << 4) + (lane & 15);
        const int rb2 = bm + (wr << 5) + (mi << 4) + ((lane >> 4) << 2);
        if (TP[job] >= 0) {
          bf16x4 pk;
#pragma unroll
          for (int jx = 0; jx < 4; ++jx) pk[jx] = f2bf(acc[mi][ni][jx]);
          short* PW = SH + SB_PW + TP[job] * 131072 + (c >> 6) * 16384;
          const int idx = (rb2 >> 5) * 2048 + (((c & 63) >> 4) << 9) + (((rb2 & 31) >> 3) << 7)
                        + ((c & 15) << 3) + (rb2 & 7);
          *(bf16x4*)(PW + idx) = pk;
        }
        if (F32[job] >= 0) {
          float* TW = ws + WF_TW + F32[job] * 131072;
#pragma unroll
          for (int jx = 0; jx < 4; ++jx)
            TW[(size_t)(rb2 + jx) * DN + c] = acc[mi][ni][jx];
        }
      }
  }
}

// ---- S23: per 64x64 output tile: c@XW + (own g-strip -> h) @ PW, tanh,
//           atomic main contributions ----
__global__ __launch_bounds__(512) void s23_k(Pk p) {
  float* ws = p.ws;
  short* SH = (short*)(ws + WF_BF);
  __shared__ __align__(16) short Cs[16384];   // c panels, later h panels (32 KB)
  __shared__ float accg[4][64][16];
  __shared__ float srs_lds[256], E_lds[256], d0_lds[64];
  const int bid = blockIdx.x, tid = threadIdx.x;
  const int lane = tid & 63, w = tid >> 6;
  const int q = w & 3, kf = w >> 2;
  const int wr = q >> 1, wc = q & 1;
  const int job = bid >> 5, t = bid & 31;
  const int bm = (t >> 3) << 6, bn = (t & 7) << 6;

  const int SRC[3] = {0, 2, 4};
  const int SRS[3] = {0, 1, 3};
  const int D0M[3] = {0, 2, 4};
  const int PWH[3] = {0, 2, 0};
  const int PWC[3] = {1, 3, 4};

  if (tid < 256) {
    const float* rp = ws + WF_RP + SRS[job] * 2048;
    float s = 1.f;
#pragma unroll
    for (int tc = 0; tc < 8; ++tc) s += rp[tc * 256 + tid];
    srs_lds[tid] = s;
  } else if (job < 2) {
    const float* ec = ws + WF_EC + job * 2048;
    float s = 0.f;
#pragma unroll
    for (int tr = 0; tr < 8; ++tr) s += ec[tr * 256 + (tid - 256)];
    E_lds[tid - 256] = s;
  }
  if (tid < 64) {
    const float* rp = ws + WF_RP + D0M[job] * 2048;
    float s = 2.f;
#pragma unroll
    for (int tc = 0; tc < 8; ++tc) s += rp[tc * 256 + bm + tid];
    d0_lds[tid] = rsqrtf(s);
  }
  __syncthreads();

  {  // stage transformed c strip [64 x 256] into Cs
    const float* src = ws + WF_S + SRC[job] * 65536;
    const int r = tid >> 3, s8 = tid & 7;
    const int qq = s8 & 3, ih = s8 >> 2;
#pragma unroll
    for (int i = 0; i < 4; ++i) {
      const int ti = i * 2 + ih;
      const int k0 = ti * 32 + (qq << 3);
      const float* pa = src + (size_t)(bm + r) * 256 + k0;
      float x[8];
      *(float4*)&x[0] = *(const float4*)pa;
      *(float4*)&x[4] = *(const float4*)(pa + 4);
      bf16x8 pk;
#pragma unroll
      for (int j = 0; j < 8; ++j) {
        const float rv = fmaxf(x[j], 0.f);
        pk[j] = f2bf(rv * rsqrtf(srs_lds[k0 + j] + rv));
      }
      *(bf16x8*)&Cs[ti * 2048 + ((r >> 4) << 9) + (qq << 7) + ((r & 15) << 3)] = pk;
    }
  }
  __syncthreads();

  // c @ XW  (quadrant q, K-half kf)
  f32x4 acc2[2][2] = {};
  const short* PWcb = SH + SB_PW + PWC[job] * 131072 + (bn >> 6) * 16384;
#pragma unroll
  for (int i = kf * 4; i < kf * 4 + 4; ++i)
    mfma_tiles(Cs + i * 2048, PWcb + i * 2048, wr, wc, lane, acc2);

  if (job < 2) {
    // own g strip: wave w computes g[64][w*32 .. w*32+32] over full K=256
    f32x4 acc16[4][2] = {};
    const short* EB = SH + SB_ETP + job * 65536 + (w >> 1) * 16384;
    const int bh = (w & 1) << 1;
#pragma unroll 2
    for (int i2 = 0; i2 < 8; ++i2) {
      const short* at = Cs + i2 * 2048;
      const short* bt = EB + i2 * 2048;
      const bf16x8 fb0 = *(const bf16x8*)(bt + ((bh + 0) << 9) + (lane << 3));
      const bf16x8 fb1 = *(const bf16x8*)(bt + ((bh + 1) << 9) + (lane << 3));
#pragma unroll
      for (int mi = 0; mi < 4; ++mi) {
        const bf16x8 fa = *(const bf16x8*)(at + (mi << 9) + (lane << 3));
        acc16[mi][0] = __builtin_amdgcn_mfma_f32_16x16x32_bf16(fa, fb0, acc16[mi][0], 0, 0, 0);
        acc16[mi][1] = __builtin_amdgcn_mfma_f32_16x16x32_bf16(fa, fb1, acc16[mi][1], 0, 0, 0);
      }
    }
    __syncthreads();
    // h for this 32-col slice -> overwrite Cs tile w (c fully consumed)
    const float* e0 = ws + WF_E + (job ? 2 : 0) * 65536;
    short* Ht = Cs + w * 2048;
#pragma unroll
    for (int mi = 0; mi < 4; ++mi)
#pragma unroll
      for (int nj = 0; nj < 2; ++nj) {
        const int kc = (nj << 4) + (lane & 15);
        const int col = (w << 5) + kc;
#pragma unroll
        for (int jx = 0; jx < 4; ++jx) {
          const int row = (mi << 4) + ((lane >> 4) << 2) + jx;
          const float e = e0[(size_t)(bm + row) * 256 + col];
          const float hv = (2.f * d0_lds[row] * e + acc16[mi][nj][jx]) / (e + E_lds[col]);
          Ht[((row >> 4) << 9) + ((kc >> 3) << 7) + ((row & 15) << 3) + (kc & 7)] = f2bf(hv);
        }
      }
    __syncthreads();
    // h @ PWh into same accumulator
    const short* PWhb = SH + SB_PW + PWH[job] * 131072 + (bn >> 6) * 16384;
#pragma unroll
    for (int i = kf * 4; i < kf * 4 + 4; ++i)
      mfma_tiles(Cs + i * 2048, PWhb + i * 2048, wr, wc, lane, acc2);
  }

  if (kf) {
#pragma unroll
    for (int mi = 0; mi < 2; ++mi)
#pragma unroll
      for (int ni = 0; ni < 2; ++ni)
#pragma unroll
        for (int jx = 0; jx < 4; ++jx)
          accg[q][lane][(mi * 2 + ni) * 4 + jx] = acc2[mi][ni][jx];
  }
  __syncthreads();
  if (kf) return;
#pragma unroll
  for (int mi = 0; mi < 2; ++mi)
#pragma unroll
    for (int ni = 0; ni < 2; ++ni)
#pragma unroll
      for (int jx = 0; jx < 4; ++jx)
        acc2[mi][ni][jx] += accg[q][lane][(mi * 2 + ni) * 4 + jx];

  const float* TW = ws + WF_TW + job * 131072;
  const float* bias = (job == 0) ? p.b_tt : (job == 1) ? p.b_it : p.b_ntt;
  float* O = p.out + (size_t)(job + 1) * CN * DN;
  const float coef = (job == 0) ? 0.35f : 0.15f;
#pragma unroll
  for (int mi = 0; mi < 2; ++mi)
#pragma unroll
    for (int ni = 0; ni < 2; ++ni) {
      const int cl = (wc << 5) + (ni << 4) + (lane & 15);
      const int rb = (wr << 5) + (mi << 4) + ((lane >> 4) << 2);
#pragma unroll
      for (int jx = 0; jx < 4; ++jx) {
        const int rl = rb + jx;
        const size_t idx = (size_t)(bm + rl) * DN + bn + cl;
        const float d = d0_lds[rl];
        const float o = tanhf(d * (acc2[mi][ni][jx] + 2.f * d * TW[idx]) + bias[idx]);
        O[idx] = o;
        if (job < 2) atomicAdd(p.out + idx, coef * o);
      }
    }
}

extern "C" void kernel_launch(void* const* d_in, const int* in_sizes, int n_in,
                              void* d_out, int out_size, void* d_ws, size_t ws_size,
                              hipStream_t stream) {
  Pk prm;
  prm.img_feature = (const float*)d_in[0];
  prm.text  = (const float*)d_in[1];
  prm.img   = (const float*)d_in[2];
  prm.neg   = (const float*)d_in[3];
  prm.p_t   = (const float*)d_in[4];
  prm.aw_t  = (const float*)d_in[5];
  prm.ab_t  = (const float*)d_in[6];
  prm.p_i   = (const float*)d_in[7];
  prm.aw_i  = (const float*)d_in[8];
  prm.ab_i  = (const float*)d_in[9];
  prm.W_tt  = (const float*)d_in[10];
  prm.b_tt  = (const float*)d_in[11];
  prm.W_it  = (const float*)d_in[12];
  prm.b_it  = (const float*)d_in[13];
  prm.W_ntt = (const float*)d_in[14];
  prm.b_ntt = (const float*)d_in[15];
  prm.out = (float*)d_out;
  prm.ws  = (float*)d_ws;

  s1_k<<<352, 512, 0, stream>>>(prm);
  s23_k<<<96, 512, 0, stream>>>(prm);
}

// Round 12
// 39.291 us; speedup vs baseline: 1.8487x; 1.0093x over previous
//
#include <hip/hip_runtime.h>
#include <math.h>

#define CN 256
#define DN 512

typedef __attribute__((ext_vector_type(8))) short bf16x8;
typedef __attribute__((ext_vector_type(4))) short bf16x4;
typedef __attribute__((ext_vector_type(4))) float f32x4;

__device__ __forceinline__ short f2bf(float f) {
  unsigned u = __float_as_uint(f);
  u += 0x7fffu + ((u >> 16) & 1u);
  return (short)(u >> 16);
}

__device__ __forceinline__ bf16x8 pack8(float4 a, float4 b) {
  bf16x8 r;
  r[0] = f2bf(a.x); r[1] = f2bf(a.y); r[2] = f2bf(a.z); r[3] = f2bf(a.w);
  r[4] = f2bf(b.x); r[5] = f2bf(b.y); r[6] = f2bf(b.z); r[7] = f2bf(b.w);
  return r;
}

__device__ __forceinline__ float d4(float4 v) {
  return v.x * v.x + v.y * v.y + v.z * v.z + v.w * v.w;
}

struct Pk {
  const float *img_feature, *text, *img, *neg;
  const float *p_t, *aw_t, *ab_t, *p_i, *aw_i, *ab_i;
  const float *W_tt, *b_tt, *W_it, *b_it, *W_ntt, *b_ntt;
  float* out; float* ws;
};

// ---- f32 workspace (float offsets) ----
#define WF_S   0
#define WF_E   327680
#define WF_RP  524288
#define WF_EC  534528
#define WF_TW  540672
#define WF_BF  933888

// ---- bf16 panel region (short offsets) ----
#define SB_ETP   1703936
#define SB_PW    1966080

__device__ __forceinline__ void mfma_tiles(const short* at, const short* bt,
                                           int wr, int wc, int lane, f32x4 (&acc)[2][2]) {
  const bf16x8 fa0 = *(const bf16x8*)(at + ((wr << 1) << 9) + (lane << 3));
  const bf16x8 fa1 = *(const bf16x8*)(at + (((wr << 1) + 1) << 9) + (lane << 3));
  const bf16x8 fb0 = *(const bf16x8*)(bt + ((wc << 1) << 9) + (lane << 3));
  const bf16x8 fb1 = *(const bf16x8*)(bt + (((wc << 1) + 1) << 9) + (lane << 3));
  acc[0][0] = __builtin_amdgcn_mfma_f32_16x16x32_bf16(fa0, fb0, acc[0][0], 0, 0, 0);
  acc[0][1] = __builtin_amdgcn_mfma_f32_16x16x32_bf16(fa0, fb1, acc[0][1], 0, 0, 0);
  acc[1][0] = __builtin_amdgcn_mfma_f32_16x16x32_bf16(fa1, fb0, acc[1][0], 0, 0, 0);
  acc[1][1] = __builtin_amdgcn_mfma_f32_16x16x32_bf16(fa1, fb1, acc[1][1], 0, 0, 0);
}

// ---- S1: 8 NT GEMMs + 7 pre-GEMMs, register-prefetch pipelined staging ----
__global__ __launch_bounds__(512) void s1_k(Pk p) {
  float* ws = p.ws;
  short* SH = (short*)(ws + WF_BF);
  __shared__ __align__(16) short As[8192];
  __shared__ __align__(16) short Bs[8192];
  __shared__ float accx[4][64][16];
  __shared__ float invA_lds[64], invB_lds[64];
  const int bid = blockIdx.x, tid = threadIdx.x;
  const int lane = tid & 63, w = tid >> 6;
  const int q = w & 3, kh = w >> 2;
  const int wr = q >> 1, wc = q & 1;
  const int sr = (tid & 255) >> 2, sq = tid & 3;

  const float* XL[7] = {p.text, p.img, p.neg, p.aw_t, p.aw_i, p.p_t, p.p_i};

  if (bid < 128) {
    const int job = bid >> 4, tile = bid & 15;
    const int bm = (tile >> 2) << 6, bn = (tile & 3) << 6;
    if (tid < 256) p.out[4 * CN * DN + bid * 256 + tid] = p.img_feature[bid * 256 + tid];
    {
      const int i0 = bid * 1024 + tid;
      p.out[i0] = 0.5f * p.text[i0];
      p.out[i0 + 512] = 0.5f * p.text[i0 + 512];
    }

    const int AM[8] = {0, 1, 0, 2, 0, 0, 1, 0};
    const int BM[8] = {0, 1, 1, 2, 2, 3, 4, 4};
    const float* A = XL[AM[job]];
    const float* B = XL[BM[job]];
    const float* srcT = (tid < 256 ? A + (size_t)(bm + sr) * 512
                                   : B + (size_t)(bn + sr) * 512) + (sq << 3);
    short* dst = (tid < 256) ? As : Bs;
    f32x4 acc[2][2] = {};
    float ss = 0.f;
    float4 r0[8];
#pragma unroll
    for (int ks = 0; ks < 4; ++ks) {
      r0[2 * ks]     = *(const float4*)(srcT + ks * 32);
      r0[2 * ks + 1] = *(const float4*)(srcT + ks * 32 + 4);
    }
    for (int ck = 0; ck < 4; ++ck) {
#pragma unroll
      for (int ks = 0; ks < 4; ++ks) {
        ss += d4(r0[2 * ks]) + d4(r0[2 * ks + 1]);
        *(bf16x8*)&dst[ks * 2048 + ((sr >> 4) << 9) + (sq << 7) + ((sr & 15) << 3)]
            = pack8(r0[2 * ks], r0[2 * ks + 1]);
      }
      __syncthreads();
      if (ck < 3) {
        const float* s2 = srcT + (ck + 1) * 128;
#pragma unroll
        for (int ks = 0; ks < 4; ++ks) {
          r0[2 * ks]     = *(const float4*)(s2 + ks * 32);
          r0[2 * ks + 1] = *(const float4*)(s2 + ks * 32 + 4);
        }
      }
#pragma unroll
      for (int t3 = kh * 2; t3 < kh * 2 + 2; ++t3)
        mfma_tiles(As + t3 * 2048, Bs + t3 * 2048, wr, wc, lane, acc);
      __syncthreads();
    }

    if (job < 5) {
      ss += __shfl_xor(ss, 1, 64);
      ss += __shfl_xor(ss, 2, 64);
      if (sq == 0) {
        const float iv = 1.f / fmaxf(sqrtf(ss), 1e-12f);
        if (tid < 256) invA_lds[sr] = iv;
        else           invB_lds[sr] = iv;
      }
    }
    if (kh) {
#pragma unroll
      for (int mi = 0; mi < 2; ++mi)
#pragma unroll
        for (int ni = 0; ni < 2; ++ni)
#pragma unroll
          for (int jx = 0; jx < 4; ++jx)
            accx[q][lane][(mi * 2 + ni) * 4 + jx] = acc[mi][ni][jx];
    }
    __syncthreads();
    if (kh) return;
#pragma unroll
    for (int mi = 0; mi < 2; ++mi)
#pragma unroll
      for (int ni = 0; ni < 2; ++ni)
#pragma unroll
        for (int jx = 0; jx < 4; ++jx)
          acc[mi][ni][jx] += accx[q][lane][(mi * 2 + ni) * 4 + jx];

    float sv[2][2][4];
    if (job < 5) {
      float* C = ws + WF_S + job * 65536;
#pragma unroll
      for (int mi = 0; mi < 2; ++mi)
#pragma unroll
        for (int ni = 0; ni < 2; ++ni) {
          const int cl = (wc << 5) + (ni << 4) + (lane & 15);
#pragma unroll
          for (int jx = 0; jx < 4; ++jx) {
            const int rl = (wr << 5) + (mi << 4) + ((lane >> 4) << 2) + jx;
            const float v = acc[mi][ni][jx] * invA_lds[rl] * invB_lds[cl];
            sv[mi][ni][jx] = v;
            C[(size_t)(bm + rl) * CN + bn + cl] = v;
          }
        }
      float* rp = ws + WF_RP + job * 2048 + ((bn >> 5) + wc) * 256;
#pragma unroll
      for (int mi = 0; mi < 2; ++mi)
#pragma unroll
        for (int jx = 0; jx < 4; ++jx) {
          float s = fmaxf(sv[mi][0][jx], 0.f) + fmaxf(sv[mi][1][jx], 0.f);
          s += __shfl_xor(s, 1, 64); s += __shfl_xor(s, 2, 64);
          s += __shfl_xor(s, 4, 64); s += __shfl_xor(s, 8, 64);
          if ((lane & 15) == 0) {
            const int rl = (wr << 5) + (mi << 4) + ((lane >> 4) << 2) + jx;
            rp[bm + rl] = s;
          }
        }
    } else {
      const int z = job - 5;
      const float* bias = (job == 5) ? p.ab_t : p.ab_i;
      float* C = ws + WF_E + z * 65536;
#pragma unroll
      for (int mi = 0; mi < 2; ++mi)
#pragma unroll
        for (int ni = 0; ni < 2; ++ni) {
          const int cl = (wc << 5) + (ni << 4) + (lane & 15);
          const int rb2 = (wr << 5) + (mi << 4) + ((lane >> 4) << 2);
#pragma unroll
          for (int jx = 0; jx < 4; ++jx) {
            const float v = expf(acc[mi][ni][jx] + bias[bn + cl]);
            sv[mi][ni][jx] = v;
            C[(size_t)(bm + rb2 + jx) * CN + bn + cl] = v;
          }
          if (z < 2) {
            bf16x4 pk;
#pragma unroll
            for (int jx = 0; jx < 4; ++jx) pk[jx] = f2bf(sv[mi][ni][jx]);
            short* ET = SH + SB_ETP + z * 65536 + (bn >> 6) * 16384 + (bm >> 5) * 2048;
            const int idx = (rb2 >> 5) * 2048 + ((cl >> 4) << 9) + (((rb2 & 31) >> 3) << 7)
                          + ((cl & 15) << 3) + (rb2 & 7);
            *(bf16x4*)(ET + idx) = pk;
          }
        }
      if (z < 2) {
        float* ec = ws + WF_EC + z * 2048 + ((bm >> 5) + wr) * 256;
#pragma unroll
        for (int ni = 0; ni < 2; ++ni) {
          float s = 0.f;
#pragma unroll
          for (int mi = 0; mi < 2; ++mi)
#pragma unroll
            for (int jx = 0; jx < 4; ++jx) s += sv[mi][ni][jx];
          s += __shfl_xor(s, 16, 64); s += __shfl_xor(s, 32, 64);
          if ((lane >> 4) == 0) ec[bn + (wc << 5) + (ni << 4) + (lane & 15)] = s;
        }
      }
    }
  } else {
    // pre-GEMMs: X@W, 64x64 tiles, pipelined
    const int t2 = bid - 128, job = t2 >> 5, tile = t2 & 31;
    const int bm = (tile >> 3) << 6, bn = (tile & 7) << 6;
    const int AJ[7] = {5, 0, 6, 1, 0, 2, 0};
    const int WJ[7] = {0, 0, 1, 1, 1, 2, 2};
    const int TP[7] = {0, 1, 2, 3, -1, 4, -1};
    const int F32[7] = {-1, 0, -1, -1, 1, -1, 2};
    const float* A = XL[AJ[job]];
    const float* W = (WJ[job] == 0) ? p.W_tt : (WJ[job] == 1) ? p.W_it : p.W_ntt;
    const int wv4 = w & 3;
    const int d = bn + lane;
    f32x4 acc[2][2] = {};
    const float* srcA = A + (size_t)(bm + sr) * 512 + (sq << 3);
    float4 ra[8];
    float wreg[32];
    if (tid < 256) {
#pragma unroll
      for (int ks = 0; ks < 4; ++ks) {
        ra[2 * ks]     = *(const float4*)(srcA + ks * 32);
        ra[2 * ks + 1] = *(const float4*)(srcA + ks * 32 + 4);
      }
    } else {
#pragma unroll
      for (int c = 0; c < 4; ++c) {
        const int m0 = wv4 * 32 + c * 8;
#pragma unroll
        for (int j = 0; j < 8; ++j) wreg[c * 8 + j] = W[(size_t)(m0 + j) * 512 + d];
      }
    }
    for (int ck = 0; ck < 4; ++ck) {
      if (tid < 256) {
#pragma unroll
        for (int ks = 0; ks < 4; ++ks)
          *(bf16x8*)&As[ks * 2048 + ((sr >> 4) << 9) + (sq << 7) + ((sr & 15) << 3)]
              = pack8(ra[2 * ks], ra[2 * ks + 1]);
      } else {
#pragma unroll
        for (int c = 0; c < 4; ++c) {
          bf16x8 pk;
#pragma unroll
          for (int j = 0; j < 8; ++j) pk[j] = f2bf(wreg[c * 8 + j]);
          *(bf16x8*)&Bs[wv4 * 2048 + ((lane >> 4) << 9) + (c << 7) + ((lane & 15) << 3)] = pk;
        }
      }
      __syncthreads();
      if (ck < 3) {
        if (tid < 256) {
          const float* s2 = srcA + (ck + 1) * 128;
#pragma unroll
          for (int ks = 0; ks < 4; ++ks) {
            ra[2 * ks]     = *(const float4*)(s2 + ks * 32);
            ra[2 * ks + 1] = *(const float4*)(s2 + ks * 32 + 4);
          }
        } else {
#pragma unroll
          for (int c = 0; c < 4; ++c) {
            const int m0 = (ck + 1) * 128 + wv4 * 32 + c * 8;
#pragma unroll
            for (int j = 0; j < 8; ++j) wreg[c * 8 + j] = W[(size_t)(m0 + j) * 512 + d];
          }
        }
      }
#pragma unroll
      for (int t3 = kh * 2; t3 < kh * 2 + 2; ++t3)
        mfma_tiles(As + t3 * 2048, Bs + t3 * 2048, wr, wc, lane, acc);
      __syncthreads();
    }
    if (kh) {
#pragma unroll
      for (int mi = 0; mi < 2; ++mi)
#pragma unroll
        for (int ni = 0; ni < 2; ++ni)
#pragma unroll
          for (int jx = 0; jx < 4; ++jx)
            accx[q][lane][(mi * 2 + ni) * 4 + jx] = acc[mi][ni][jx];
    }
    __syncthreads();
    if (kh) return;
#pragma unroll
    for (int mi = 0; mi < 2; ++mi)
#pragma unroll
      for (int ni = 0; ni < 2; ++ni)
#pragma unroll
        for (int jx = 0; jx < 4; ++jx)
          acc[mi][ni][jx] += accx[q][lane][(mi * 2 + ni) * 4 + jx];
#pragma unroll
    for (int mi = 0; mi < 2; ++mi)
#pragma unroll
      for (int ni = 0; ni < 2; ++ni) {
        const int c = bn + (wc << 5) + (ni << 4) + (lane & 15);
        const int rb2 = bm + (wr << 5) + (mi << 4) + ((lane >> 4) << 2);
        if (TP[job] >= 0) {
          bf16x4 pk;
#pragma unroll
          for (int jx = 0; jx < 4; ++jx) pk[jx] = f2bf(acc[mi][ni][jx]);
          short* PW = SH + SB_PW + TP[job] * 131072 + (c >> 6) * 16384;
          const int idx = (rb2 >> 5) * 2048 + (((c & 63) >> 4) << 9) + (((rb2 & 31) >> 3) << 7)
                        + ((c & 15) << 3) + (rb2 & 7);
          *(bf16x4*)(PW + idx) = pk;
        }
        if (F32[job] >= 0) {
          float* TW = ws + WF_TW + F32[job] * 131072;
#pragma unroll
          for (int jx = 0; jx < 4; ++jx)
            TW[(size_t)(rb2 + jx) * DN + c] = acc[mi][ni][jx];
        }
      }
  }
}

// ---- S23: c@XW + (own g-strip -> h) @ PW, tanh, atomic main ----
__global__ __launch_bounds__(512) void s23_k(Pk p) {
  float* ws = p.ws;
  short* SH = (short*)(ws + WF_BF);
  __shared__ __align__(16) short Cs[16384];
  __shared__ float accg[4][64][16];
  __shared__ float srs_lds[256], E_lds[256], d0_lds[64];
  const int bid = blockIdx.x, tid = threadIdx.x;
  const int lane = tid & 63, w = tid >> 6;
  const int q = w & 3, kf = w >> 2;
  const int wr = q >> 1, wc = q & 1;
  const int job = bid >> 5, t = bid & 31;
  const int bm = (t >> 3) << 6, bn = (t & 7) << 6;

  const int SRC[3] = {0, 2, 4};
  const int SRS[3] = {0, 1, 3};
  const int D0M[3] = {0, 2, 4};
  const int PWH[3] = {0, 2, 0};
  const int PWC[3] = {1, 3, 4};

  // issue c-strip loads first (independent of partials)
  const int r = tid >> 3, s8 = tid & 7;
  const int qq = s8 & 3, ih = s8 >> 2;
  const float* srcc = ws + WF_S + SRC[job] * 65536 + (size_t)(bm + r) * 256;
  float xr[32];
#pragma unroll
  for (int i = 0; i < 4; ++i) {
    const int k0 = (i * 2 + ih) * 32 + (qq << 3);
    *(float4*)&xr[i * 8]     = *(const float4*)(srcc + k0);
    *(float4*)&xr[i * 8 + 4] = *(const float4*)(srcc + k0 + 4);
  }

  if (tid < 256) {
    const float* rp = ws + WF_RP + SRS[job] * 2048;
    float s = 1.f;
#pragma unroll
    for (int tc = 0; tc < 8; ++tc) s += rp[tc * 256 + tid];
    srs_lds[tid] = s;
  } else if (job < 2) {
    const float* ec = ws + WF_EC + job * 2048;
    float s = 0.f;
#pragma unroll
    for (int tr = 0; tr < 8; ++tr) s += ec[tr * 256 + (tid - 256)];
    E_lds[tid - 256] = s;
  }
  if (tid < 64) {
    const float* rp = ws + WF_RP + D0M[job] * 2048;
    float s = 2.f;
#pragma unroll
    for (int tc = 0; tc < 8; ++tc) s += rp[tc * 256 + bm + tid];
    d0_lds[tid] = rsqrtf(s);
  }
  __syncthreads();

  {  // transform + store c strip
#pragma unroll
    for (int i = 0; i < 4; ++i) {
      const int ti = i * 2 + ih;
      const int k0 = ti * 32 + (qq << 3);
      bf16x8 pk;
#pragma unroll
      for (int j = 0; j < 8; ++j) {
        const float rv = fmaxf(xr[i * 8 + j], 0.f);
        pk[j] = f2bf(rv * rsqrtf(srs_lds[k0 + j] + rv));
      }
      *(bf16x8*)&Cs[ti * 2048 + ((r >> 4) << 9) + (qq << 7) + ((r & 15) << 3)] = pk;
    }
  }
  __syncthreads();

  // prefetch e0 for h epilogue (job<2), hidden under the GEMMs below
  float er[4][2][4];
  if (job < 2) {
    const float* e0 = ws + WF_E + (job ? 2 : 0) * 65536;
#pragma unroll
    for (int mi = 0; mi < 4; ++mi)
#pragma unroll
      for (int nj = 0; nj < 2; ++nj) {
        const int col = (w << 5) + (nj << 4) + (lane & 15);
#pragma unroll
        for (int jx = 0; jx < 4; ++jx) {
          const int row = (mi << 4) + ((lane >> 4) << 2) + jx;
          er[mi][nj][jx] = e0[(size_t)(bm + row) * 256 + col];
        }
      }
  }

  // c @ XW  (quadrant q, K-half kf)
  f32x4 acc2[2][2] = {};
  const short* PWcb = SH + SB_PW + PWC[job] * 131072 + (bn >> 6) * 16384;
#pragma unroll
  for (int i = kf * 4; i < kf * 4 + 4; ++i)
    mfma_tiles(Cs + i * 2048, PWcb + i * 2048, wr, wc, lane, acc2);

  if (job < 2) {
    // own g strip: wave w computes g[64][w*32 .. w*32+32] over full K=256
    f32x4 acc16[4][2] = {};
    const short* EB = SH + SB_ETP + job * 65536 + (w >> 1) * 16384;
    const int bh = (w & 1) << 1;
#pragma unroll
    for (int i2 = 0; i2 < 8; ++i2) {
      const short* at = Cs + i2 * 2048;
      const short* bt = EB + i2 * 2048;
      const bf16x8 fb0 = *(const bf16x8*)(bt + ((bh + 0) << 9) + (lane << 3));
      const bf16x8 fb1 = *(const bf16x8*)(bt + ((bh + 1) << 9) + (lane << 3));
#pragma unroll
      for (int mi = 0; mi < 4; ++mi) {
        const bf16x8 fa = *(const bf16x8*)(at + (mi << 9) + (lane << 3));
        acc16[mi][0] = __builtin_amdgcn_mfma_f32_16x16x32_bf16(fa, fb0, acc16[mi][0], 0, 0, 0);
        acc16[mi][1] = __builtin_amdgcn_mfma_f32_16x16x32_bf16(fa, fb1, acc16[mi][1], 0, 0, 0);
      }
    }
    __syncthreads();
    short* Ht = Cs + w * 2048;
#pragma unroll
    for (int mi = 0; mi < 4; ++mi)
#pragma unroll
      for (int nj = 0; nj < 2; ++nj) {
        const int kc = (nj << 4) + (lane & 15);
        const int col = (w << 5) + kc;
#pragma unroll
        for (int jx = 0; jx < 4; ++jx) {
          const int row = (mi << 4) + ((lane >> 4) << 2) + jx;
          const float e = er[mi][nj][jx];
          const float hv = (2.f * d0_lds[row] * e + acc16[mi][nj][jx]) / (e + E_lds[col]);
          Ht[((row >> 4) << 9) + ((kc >> 3) << 7) + ((row & 15) << 3) + (kc & 7)] = f2bf(hv);
        }
      }
    __syncthreads();
    const short* PWhb = SH + SB_PW + PWH[job] * 131072 + (bn >> 6) * 16384;
#pragma unroll
    for (int i = kf * 4; i < kf * 4 + 4; ++i)
      mfma_tiles(Cs + i * 2048, PWhb + i * 2048, wr, wc, lane, acc2);
  }

  if (kf) {
#pragma unroll
    for (int mi = 0; mi < 2; ++mi)
#pragma unroll
      for (int ni = 0; ni < 2; ++ni)
#pragma unroll
        for (int jx = 0; jx < 4; ++jx)
          accg[q][lane][(mi * 2 + ni) * 4 + jx] = acc2[mi][ni][jx];
  }
  __syncthreads();
  if (kf) return;
#pragma unroll
  for (int mi = 0; mi < 2; ++mi)
#pragma unroll
    for (int ni = 0; ni < 2; ++ni)
#pragma unroll
      for (int jx = 0; jx < 4; ++jx)
        acc2[mi][ni][jx] += accg[q][lane][(mi * 2 + ni) * 4 + jx];

  const float* TW = ws + WF_TW + job * 131072;
  const float* bias = (job == 0) ? p.b_tt : (job == 1) ? p.b_it : p.b_ntt;
  float* O = p.out + (size_t)(job + 1) * CN * DN;
  const float coef = (job == 0) ? 0.35f : 0.15f;
#pragma unroll
  for (int mi = 0; mi < 2; ++mi)
#pragma unroll
    for (int ni = 0; ni < 2; ++ni) {
      const int cl = (wc << 5) + (ni << 4) + (lane & 15);
      const int rb = (wr << 5) + (mi << 4) + ((lane >> 4) << 2);
#pragma unroll
      for (int jx = 0; jx < 4; ++jx) {
        const int rl = rb + jx;
        const size_t idx = (size_t)(bm + rl) * DN + bn + cl;
        const float d = d0_lds[rl];
        const float o = tanhf(d * (acc2[mi][ni][jx] + 2.f * d * TW[idx]) + bias[idx]);
        O[idx] = o;
        if (job < 2) atomicAdd(p.out + idx, coef * o);
      }
    }
}

extern "C" void kernel_launch(void* const* d_in, const int* in_sizes, int n_in,
                              void* d_out, int out_size, void* d_ws, size_t ws_size,
                              hipStream_t stream) {
  Pk prm;
  prm.img_feature = (const float*)d_in[0];
  prm.text  = (const float*)d_in[1];
  prm.img   = (const float*)d_in[2];
  prm.neg   = (const float*)d_in[3];
  prm.p_t   = (const float*)d_in[4];
  prm.aw_t  = (const float*)d_in[5];
  prm.ab_t  = (const float*)d_in[6];
  prm.p_i   = (const float*)d_in[7];
  prm.aw_i  = (const float*)d_in[8];
  prm.ab_i  = (const float*)d_in[9];
  prm.W_tt  = (const float*)d_in[10];
  prm.b_tt  = (const float*)d_in[11];
  prm.W_it  = (const float*)d_in[12];
  prm.b_it  = (const float*)d_in[13];
  prm.W_ntt = (const float*)d_in[14];
  prm.b_ntt = (const float*)d_in[15];
  prm.out = (float*)d_out;
  prm.ws  = (float*)d_ws;

  s1_k<<<352, 512, 0, stream>>>(prm);
  s23_k<<<96, 512, 0, stream>>>(prm);
}